// Round 2
// baseline (1818.571 us; speedup 1.0000x reference)
//
#include <hip/hip_runtime.h>
#include <math.h>

#define EPSF 1e-15f

// ---------------------------------------------------------------------------
// prep: transpose W1 [64][320] -> W1t [320][64], W2/W3 [64][64] -> [64][64]^T
// so inner-loop weight reads are wave-uniform (scalarize to s_load).
// ---------------------------------------------------------------------------
__global__ void prep_kernel(const float* __restrict__ W1,
                            const float* __restrict__ W2,
                            const float* __restrict__ W3,
                            float* __restrict__ W1t,
                            float* __restrict__ W2t,
                            float* __restrict__ W3t) {
    int idx = blockIdx.x * blockDim.x + threadIdx.x;
    if (idx < 320 * 64) {
        int k = idx >> 6, j = idx & 63;
        W1t[idx] = W1[j * 320 + k];
    } else if (idx < 320 * 64 + 4096) {
        int r = idx - 320 * 64;
        int k = r >> 6, j = r & 63;
        W2t[r] = W2[j * 64 + k];
    } else if (idx < 320 * 64 + 8192) {
        int r = idx - 320 * 64 - 4096;
        int k = r >> 6, j = r & 63;
        W3t[r] = W3[j * 64 + k];
    }
}

// ---------------------------------------------------------------------------
// one mobius-linear "stage" applied to v (in registers):
//   h  = expmap0(v);  x = projx(relu(h));  t = logmap0(x);  v = t @ Wt + b
// ---------------------------------------------------------------------------
__device__ __forceinline__ void mlp_stage(float (&v)[64],
                                          const float* __restrict__ Wt,
                                          const float* __restrict__ b,
                                          float sc, float maxn) {
    float n2 = 0.f;
#pragma unroll
    for (int j = 0; j < 64; ++j) n2 = fmaf(v[j], v[j], n2);
    float n  = sqrtf(n2);
    float he = tanhf(sc * n) / (n * sc + EPSF);   // expmap0 elementwise factor

    float t[64];
    float rn2 = 0.f;
#pragma unroll
    for (int j = 0; j < 64; ++j) {
        float h = fmaxf(he * v[j], 0.f);          // relu
        t[j] = h;
        rn2 = fmaf(h, h, rn2);
    }
    float rn = sqrtf(rn2);
    float ps = fminf(maxn / fmaxf(rn, EPSF), 1.0f);   // projx scale
    float pn = rn * ps;                                // norm after projx
    float g  = atanhf(fminf(sc * pn, 1.0f - 1e-5f)) / (sc * (pn + EPSF));
    float f  = ps * g;                                 // combined factor on t

#pragma unroll
    for (int j = 0; j < 64; ++j) v[j] = b[j];
#pragma unroll
    for (int k = 0; k < 64; ++k) {
        float tk = f * t[k];
        const float* w = Wt + k * 64;
#pragma unroll
        for (int j = 0; j < 64; ++j) v[j] = fmaf(tk, w[j], v[j]);
    }
}

// ---------------------------------------------------------------------------
// edge kernel: one thread per edge, everything in registers.
// __launch_bounds__(256, 2): 2 waves/SIMD -> 256-VGPR cap; the live set
// (128 accumulators + temps ~ 160) fits without scratch spills.
// ---------------------------------------------------------------------------
__global__ void __launch_bounds__(256, 2)
edge_kernel(const float* __restrict__ hV, const float* __restrict__ hE,
            const int* __restrict__ src, const int* __restrict__ dst,
            const float* __restrict__ logc,
            const float* __restrict__ W1t, const float* __restrict__ b1,
            const float* __restrict__ W2t, const float* __restrict__ b2,
            const float* __restrict__ W3t, const float* __restrict__ b3,
            float* __restrict__ sums, float* __restrict__ counts,
            int n_edges) {
    int e = blockIdx.x * blockDim.x + threadIdx.x;
    if (e >= n_edges) return;

    float c    = expf(logc[0]);
    float sc   = sqrtf(c);
    float maxn = (1.0f - 1e-5f) / sc;

    int s = src[e], d = dst[e];
    const float4* hE4 = reinterpret_cast<const float4*>(hE) + (size_t)e * 48;
    const float4* hVs = reinterpret_cast<const float4*>(hV) + (size_t)s * 16;
    const float4* hVd = reinterpret_cast<const float4*>(hV) + (size_t)d * 16;

    // projx scales for the two gathered node rows (rows are L1/L2-hot, re-read below)
    float ssqS = 0.f, ssqD = 0.f;
#pragma unroll
    for (int q = 0; q < 16; ++q) {
        float4 a = hVs[q];
        ssqS += a.x * a.x + a.y * a.y + a.z * a.z + a.w * a.w;
        float4 bb = hVd[q];
        ssqD += bb.x * bb.x + bb.y * bb.y + bb.z * bb.z + bb.w * bb.w;
    }
    float sS = fminf(maxn / fmaxf(sqrtf(ssqS), EPSF), 1.0f);
    float sD = fminf(maxn / fmaxf(sqrtf(ssqD), EPSF), 1.0f);

    // GEMM1 with scales deferred: AE accumulates raw h_E dots (scale sE*g
    // applied after ssqE is known), AV accumulates projx-scaled node dots.
    float AE[64], AV[64];
#pragma unroll
    for (int j = 0; j < 64; ++j) { AE[j] = 0.f; AV[j] = 0.f; }

    float ssqE = 0.f, ssqV = 0.f;

    for (int q = 0; q < 48; ++q) {           // h_E segment, k in [0,192)
        float4 x = hE4[q];
        ssqE += x.x * x.x + x.y * x.y + x.z * x.z + x.w * x.w;
        const float* w = W1t + q * 4 * 64;
#pragma unroll
        for (int j = 0; j < 64; ++j) {
            float a = AE[j];
            a = fmaf(x.x, w[j], a);
            a = fmaf(x.y, w[64 + j], a);
            a = fmaf(x.z, w[128 + j], a);
            a = fmaf(x.w, w[192 + j], a);
            AE[j] = a;
        }
    }
    for (int q = 0; q < 16; ++q) {           // src segment, k in [192,256)
        float4 x = hVs[q];
        x.x *= sS; x.y *= sS; x.z *= sS; x.w *= sS;
        ssqV += x.x * x.x + x.y * x.y + x.z * x.z + x.w * x.w;
        const float* w = W1t + (192 + q * 4) * 64;
#pragma unroll
        for (int j = 0; j < 64; ++j) {
            float a = AV[j];
            a = fmaf(x.x, w[j], a);
            a = fmaf(x.y, w[64 + j], a);
            a = fmaf(x.z, w[128 + j], a);
            a = fmaf(x.w, w[192 + j], a);
            AV[j] = a;
        }
    }
    for (int q = 0; q < 16; ++q) {           // dst segment, k in [256,320)
        float4 x = hVd[q];
        x.x *= sD; x.y *= sD; x.z *= sD; x.w *= sD;
        ssqV += x.x * x.x + x.y * x.y + x.z * x.z + x.w * x.w;
        const float* w = W1t + (256 + q * 4) * 64;
#pragma unroll
        for (int j = 0; j < 64; ++j) {
            float a = AV[j];
            a = fmaf(x.x, w[j], a);
            a = fmaf(x.y, w[64 + j], a);
            a = fmaf(x.z, w[128 + j], a);
            a = fmaf(x.w, w[192 + j], a);
            AV[j] = a;
        }
    }

    float sE = fminf(maxn / fmaxf(sqrtf(ssqE), EPSF), 1.0f);
    float nt = sqrtf(sE * sE * ssqE + ssqV);           // norm of projected concat
    float g  = atanhf(fminf(sc * nt, 1.0f - 1e-5f)) / (sc * (nt + EPSF));
    float gE = g * sE;

    float v[64];
#pragma unroll
    for (int j = 0; j < 64; ++j) v[j] = fmaf(gE, AE[j], fmaf(g, AV[j], b1[j]));

    mlp_stage(v, W2t, b2, sc, maxn);   // layer 2
    mlp_stage(v, W3t, b3, sc, maxn);   // layer 3 -> v = z3 (pre-expmap of h_msg)

    // tangent = logmap0(expmap0(v)) computed faithfully (incl. clamps/EPS)
    float n2 = 0.f;
#pragma unroll
    for (int j = 0; j < 64; ++j) n2 = fmaf(v[j], v[j], n2);
    float n  = sqrtf(n2);
    float he = tanhf(sc * n) / (n * sc + EPSF);
    float hn = he * n;                                   // ||expmap0(v)||
    float g3 = atanhf(fminf(sc * hn, 1.0f - 1e-5f)) / (sc * (hn + EPSF));
    float f3 = g3 * he;

    float* srow = sums + (size_t)s * 64;
#pragma unroll
    for (int j = 0; j < 64; ++j) atomicAdd(&srow[j], f3 * v[j]);
    atomicAdd(&counts[s], 1.0f);
}

// ---------------------------------------------------------------------------
// node kernel: agg = expmap0(sums/max(cnt,1)); out = projx(mobius_add(projx(hV), agg))
// result written in-place over xv[] to keep the live set at 128 floats.
// ---------------------------------------------------------------------------
__global__ void __launch_bounds__(256, 2)
node_kernel(const float* __restrict__ hV, const float* __restrict__ logc,
            const float* __restrict__ sums, const float* __restrict__ counts,
            float* __restrict__ out, int n_nodes) {
    int nd = blockIdx.x * blockDim.x + threadIdx.x;
    if (nd >= n_nodes) return;

    float c    = expf(logc[0]);
    float sc   = sqrtf(c);
    float maxn = (1.0f - 1e-5f) / sc;

    float inv = 1.0f / fmaxf(counts[nd], 1.0f);

    float at[64];
    float an2 = 0.f;
    const float4* sr = reinterpret_cast<const float4*>(sums) + (size_t)nd * 16;
#pragma unroll
    for (int q = 0; q < 16; ++q) {
        float4 a = sr[q];
        a.x *= inv; a.y *= inv; a.z *= inv; a.w *= inv;
        at[q * 4 + 0] = a.x; at[q * 4 + 1] = a.y;
        at[q * 4 + 2] = a.z; at[q * 4 + 3] = a.w;
        an2 += a.x * a.x + a.y * a.y + a.z * a.z + a.w * a.w;
    }
    float an = sqrtf(an2);
    float ae = tanhf(sc * an) / (an * sc + EPSF);   // y = ae * at  (agg)

    float xv[64];
    float hs2 = 0.f;
    const float4* hr = reinterpret_cast<const float4*>(hV) + (size_t)nd * 16;
#pragma unroll
    for (int q = 0; q < 16; ++q) {
        float4 a = hr[q];
        xv[q * 4 + 0] = a.x; xv[q * 4 + 1] = a.y;
        xv[q * 4 + 2] = a.z; xv[q * 4 + 3] = a.w;
        hs2 += a.x * a.x + a.y * a.y + a.z * a.z + a.w * a.w;
    }
    float sX = fminf(maxn / fmaxf(sqrtf(hs2), EPSF), 1.0f);

    float x2 = 0.f, y2 = 0.f, xy = 0.f;
#pragma unroll
    for (int j = 0; j < 64; ++j) {
        float x = sX * xv[j];
        float y = ae * at[j];
        xv[j] = x; at[j] = y;
        x2 = fmaf(x, x, x2);
        y2 = fmaf(y, y, y2);
        xy = fmaf(x, y, xy);
    }

    float ca  = 1.f + 2.f * c * xy + c * y2;
    float cb  = 1.f - c * x2;
    float den = 1.f + 2.f * c * xy + c * c * x2 * y2 + EPSF;
    float id  = 1.f / den;

    float rn2 = 0.f;
#pragma unroll
    for (int j = 0; j < 64; ++j) {
        float r = (ca * xv[j] + cb * at[j]) * id;
        xv[j] = r;                              // reuse xv as result
        rn2 = fmaf(r, r, rn2);
    }
    float rs = fminf(maxn / fmaxf(sqrtf(rn2), EPSF), 1.0f);

    float4* orow = reinterpret_cast<float4*>(out) + (size_t)nd * 16;
#pragma unroll
    for (int q = 0; q < 16; ++q) {
        float4 o;
        o.x = rs * xv[q * 4 + 0];
        o.y = rs * xv[q * 4 + 1];
        o.z = rs * xv[q * 4 + 2];
        o.w = rs * xv[q * 4 + 3];
        orow[q] = o;
    }
}

// ---------------------------------------------------------------------------
extern "C" void kernel_launch(void* const* d_in, const int* in_sizes, int n_in,
                              void* d_out, int out_size, void* d_ws, size_t ws_size,
                              hipStream_t stream) {
    const float* hV   = (const float*)d_in[0];
    const float* hE   = (const float*)d_in[1];
    const int*   src  = (const int*)d_in[2];
    const int*   dst  = (const int*)d_in[3];
    const float* logc = (const float*)d_in[4];
    const float* W1   = (const float*)d_in[5];
    const float* b1   = (const float*)d_in[6];
    const float* W2   = (const float*)d_in[7];
    const float* b2   = (const float*)d_in[8];
    const float* W3   = (const float*)d_in[9];
    const float* b3   = (const float*)d_in[10];

    int n_nodes = in_sizes[0] / 64;
    int n_edges = in_sizes[2];
    float* out = (float*)d_out;

    float* ws     = (float*)d_ws;
    float* sums   = ws;                                  // n_nodes*64
    float* counts = sums + (size_t)n_nodes * 64;         // n_nodes
    float* W1t    = counts + n_nodes;                    // 320*64
    float* W2t    = W1t + 320 * 64;                      // 64*64
    float* W3t    = W2t + 64 * 64;                       // 64*64

    hipMemsetAsync(sums, 0, ((size_t)n_nodes * 64 + n_nodes) * sizeof(float), stream);

    prep_kernel<<<(320 * 64 + 8192 + 255) / 256, 256, 0, stream>>>(W1, W2, W3, W1t, W2t, W3t);

    edge_kernel<<<(n_edges + 255) / 256, 256, 0, stream>>>(
        hV, hE, src, dst, logc, W1t, b1, W2t, b2, W3t, b3, sums, counts, n_edges);

    node_kernel<<<(n_nodes + 255) / 256, 256, 0, stream>>>(
        hV, logc, sums, counts, out, n_nodes);
}

// Round 3
// 869.761 us; speedup vs baseline: 2.0909x; 2.0909x over previous
//
#include <hip/hip_runtime.h>
#include <math.h>

#define EPSF 1e-15f

// ---------------------------------------------------------------------------
// prep: transpose W1 [64][320] -> W1t [320][64], W2/W3 -> [64][64]^T
// so inner-loop weight reads are wave-uniform (scalarize to s_load).
// ---------------------------------------------------------------------------
__global__ void prep_kernel(const float* __restrict__ W1,
                            const float* __restrict__ W2,
                            const float* __restrict__ W3,
                            float* __restrict__ W1t,
                            float* __restrict__ W2t,
                            float* __restrict__ W3t) {
    int idx = blockIdx.x * blockDim.x + threadIdx.x;
    if (idx < 320 * 64) {
        int k = idx >> 6, j = idx & 63;
        W1t[idx] = W1[j * 320 + k];
    } else if (idx < 320 * 64 + 4096) {
        int r = idx - 320 * 64;
        int k = r >> 6, j = r & 63;
        W2t[r] = W2[j * 64 + k];
    } else if (idx < 320 * 64 + 8192) {
        int r = idx - 320 * 64 - 4096;
        int k = r >> 6, j = r & 63;
        W3t[r] = W3[j * 64 + k];
    }
}

// ---------------------------------------------------------------------------
__device__ __forceinline__ void mlp_stage(float (&v)[64],
                                          const float* __restrict__ Wt,
                                          const float* __restrict__ b,
                                          float sc, float maxn) {
    float n2 = 0.f;
#pragma unroll
    for (int j = 0; j < 64; ++j) n2 = fmaf(v[j], v[j], n2);
    float n  = sqrtf(n2);
    float he = tanhf(sc * n) / (n * sc + EPSF);

    float t[64];
    float rn2 = 0.f;
#pragma unroll
    for (int j = 0; j < 64; ++j) {
        float h = fmaxf(he * v[j], 0.f);
        t[j] = h;
        rn2 = fmaf(h, h, rn2);
    }
    float rn = sqrtf(rn2);
    float ps = fminf(maxn / fmaxf(rn, EPSF), 1.0f);
    float pn = rn * ps;
    float g  = atanhf(fminf(sc * pn, 1.0f - 1e-5f)) / (sc * (pn + EPSF));
    float f  = ps * g;

#pragma unroll
    for (int j = 0; j < 64; ++j) v[j] = b[j];
#pragma unroll
    for (int k = 0; k < 64; ++k) {
        float tk = f * t[k];
        const float* w = Wt + k * 64;
#pragma unroll
        for (int j = 0; j < 64; ++j) v[j] = fmaf(tk, w[j], v[j]);
    }
}

// ---------------------------------------------------------------------------
// full per-edge pipeline -> tangent row tv[64] and its src node s_out
// ---------------------------------------------------------------------------
__device__ __forceinline__ void compute_tangent(
    int e, const float* __restrict__ hV, const float* __restrict__ hE,
    const int* __restrict__ src, const int* __restrict__ dst,
    float c, float sc, float maxn,
    const float* __restrict__ W1t, const float* __restrict__ b1,
    const float* __restrict__ W2t, const float* __restrict__ b2,
    const float* __restrict__ W3t, const float* __restrict__ b3,
    float (&tv)[64], int& s_out) {

    int s = src[e], d = dst[e];
    s_out = s;
    const float4* hE4 = reinterpret_cast<const float4*>(hE) + (size_t)e * 48;
    const float4* hVs = reinterpret_cast<const float4*>(hV) + (size_t)s * 16;
    const float4* hVd = reinterpret_cast<const float4*>(hV) + (size_t)d * 16;

    float ssqS = 0.f, ssqD = 0.f;
#pragma unroll
    for (int q = 0; q < 16; ++q) {
        float4 a = hVs[q];
        ssqS += a.x * a.x + a.y * a.y + a.z * a.z + a.w * a.w;
        float4 bb = hVd[q];
        ssqD += bb.x * bb.x + bb.y * bb.y + bb.z * bb.z + bb.w * bb.w;
    }
    float sS = fminf(maxn / fmaxf(sqrtf(ssqS), EPSF), 1.0f);
    float sD = fminf(maxn / fmaxf(sqrtf(ssqD), EPSF), 1.0f);

    // GEMM1 with deferred scales: AE raw h_E dots, AV projx-scaled node dots.
    float AE[64], AV[64];
#pragma unroll
    for (int j = 0; j < 64; ++j) { AE[j] = 0.f; AV[j] = 0.f; }

    float ssqE = 0.f, ssqV = 0.f;

    for (int q = 0; q < 48; ++q) {           // h_E, k in [0,192)
        float4 x = hE4[q];
        ssqE += x.x * x.x + x.y * x.y + x.z * x.z + x.w * x.w;
        const float* w = W1t + q * 4 * 64;
#pragma unroll
        for (int j = 0; j < 64; ++j) {
            float a = AE[j];
            a = fmaf(x.x, w[j], a);
            a = fmaf(x.y, w[64 + j], a);
            a = fmaf(x.z, w[128 + j], a);
            a = fmaf(x.w, w[192 + j], a);
            AE[j] = a;
        }
    }
    for (int q = 0; q < 16; ++q) {           // src, k in [192,256)
        float4 x = hVs[q];
        x.x *= sS; x.y *= sS; x.z *= sS; x.w *= sS;
        ssqV += x.x * x.x + x.y * x.y + x.z * x.z + x.w * x.w;
        const float* w = W1t + (192 + q * 4) * 64;
#pragma unroll
        for (int j = 0; j < 64; ++j) {
            float a = AV[j];
            a = fmaf(x.x, w[j], a);
            a = fmaf(x.y, w[64 + j], a);
            a = fmaf(x.z, w[128 + j], a);
            a = fmaf(x.w, w[192 + j], a);
            AV[j] = a;
        }
    }
    for (int q = 0; q < 16; ++q) {           // dst, k in [256,320)
        float4 x = hVd[q];
        x.x *= sD; x.y *= sD; x.z *= sD; x.w *= sD;
        ssqV += x.x * x.x + x.y * x.y + x.z * x.z + x.w * x.w;
        const float* w = W1t + (256 + q * 4) * 64;
#pragma unroll
        for (int j = 0; j < 64; ++j) {
            float a = AV[j];
            a = fmaf(x.x, w[j], a);
            a = fmaf(x.y, w[64 + j], a);
            a = fmaf(x.z, w[128 + j], a);
            a = fmaf(x.w, w[192 + j], a);
            AV[j] = a;
        }
    }

    float sE = fminf(maxn / fmaxf(sqrtf(ssqE), EPSF), 1.0f);
    float nt = sqrtf(sE * sE * ssqE + ssqV);
    float g  = atanhf(fminf(sc * nt, 1.0f - 1e-5f)) / (sc * (nt + EPSF));
    float gE = g * sE;

    float v[64];
#pragma unroll
    for (int j = 0; j < 64; ++j) v[j] = fmaf(gE, AE[j], fmaf(g, AV[j], b1[j]));

    mlp_stage(v, W2t, b2, sc, maxn);
    mlp_stage(v, W3t, b3, sc, maxn);

    // tangent = logmap0(expmap0(v))
    float n2 = 0.f;
#pragma unroll
    for (int j = 0; j < 64; ++j) n2 = fmaf(v[j], v[j], n2);
    float n  = sqrtf(n2);
    float he = tanhf(sc * n) / (n * sc + EPSF);
    float hn = he * n;
    float g3 = atanhf(fminf(sc * hn, 1.0f - 1e-5f)) / (sc * (hn + EPSF));
    float f3 = g3 * he;

#pragma unroll
    for (int j = 0; j < 64; ++j) tv[j] = f3 * v[j];
}

// ---------------------------------------------------------------------------
// PATH B edge kernel: stream tangent row to tg[E][64], histogram src counts.
// 64-thread blocks + __launch_bounds__(64,1): 512-VGPR cap so the ~160-float
// live set stays register-resident (R2's 108-VGPR strip-mining fix).
// ---------------------------------------------------------------------------
__global__ void __launch_bounds__(64, 1)
edge_compute_b(const float* __restrict__ hV, const float* __restrict__ hE,
               const int* __restrict__ src, const int* __restrict__ dst,
               const float* __restrict__ logc,
               const float* __restrict__ W1t, const float* __restrict__ b1,
               const float* __restrict__ W2t, const float* __restrict__ b2,
               const float* __restrict__ W3t, const float* __restrict__ b3,
               float* __restrict__ tg, int* __restrict__ cnt, int n_edges) {
    int e = blockIdx.x * 64 + threadIdx.x;
    if (e >= n_edges) return;

    float c    = expf(logc[0]);
    float sc   = sqrtf(c);
    float maxn = (1.0f - 1e-5f) / sc;

    float tv[64]; int s;
    compute_tangent(e, hV, hE, src, dst, c, sc, maxn,
                    W1t, b1, W2t, b2, W3t, b3, tv, s);

    float4* row = reinterpret_cast<float4*>(tg + (size_t)e * 64);
#pragma unroll
    for (int q = 0; q < 16; ++q)
        row[q] = make_float4(tv[q * 4], tv[q * 4 + 1], tv[q * 4 + 2], tv[q * 4 + 3]);

    atomicAdd(&cnt[s], 1);
}

// ---------------------------------------------------------------------------
// PATH A edge kernel (ws too small): LDS transpose -> row-coalesced atomics.
// ---------------------------------------------------------------------------
__global__ void __launch_bounds__(64, 1)
edge_compute_a(const float* __restrict__ hV, const float* __restrict__ hE,
               const int* __restrict__ src, const int* __restrict__ dst,
               const float* __restrict__ logc,
               const float* __restrict__ W1t, const float* __restrict__ b1,
               const float* __restrict__ W2t, const float* __restrict__ b2,
               const float* __restrict__ W3t, const float* __restrict__ b3,
               float* __restrict__ sums, float* __restrict__ counts, int n_edges) {
    __shared__ float sm[64][65];
    __shared__ int ssrc[64];

    int base = blockIdx.x * 64;
    int e = base + threadIdx.x;
    bool valid = e < n_edges;

    float c    = expf(logc[0]);
    float sc   = sqrtf(c);
    float maxn = (1.0f - 1e-5f) / sc;

    float tv[64]; int s = 0;
#pragma unroll
    for (int j = 0; j < 64; ++j) tv[j] = 0.f;
    if (valid) {
        compute_tangent(e, hV, hE, src, dst, c, sc, maxn,
                        W1t, b1, W2t, b2, W3t, b3, tv, s);
        atomicAdd(&counts[s], 1.0f);
    }
#pragma unroll
    for (int j = 0; j < 64; ++j) sm[threadIdx.x][j] = tv[j];
    ssrc[threadIdx.x] = s;
    __syncthreads();

    int nv = n_edges - base; if (nv > 64) nv = 64;
    for (int r = 0; r < nv; ++r) {
        int sr = ssrc[r];
        float val = sm[r][threadIdx.x];
        atomicAdd(&sums[(size_t)sr * 64 + threadIdx.x], val);  // 256B-coalesced row
    }
}

// ---------------------------------------------------------------------------
// CSR build: exclusive scan of cnt (single block), then scatter edge ids.
// ---------------------------------------------------------------------------
__global__ void scan_kernel(const int* __restrict__ cnt, int* __restrict__ rowptr,
                            int* __restrict__ cursor, int n) {
    __shared__ int smem[1024];
    __shared__ int carry;
    if (threadIdx.x == 0) carry = 0;
    __syncthreads();
    for (int base = 0; base < n; base += 1024) {
        int i = base + (int)threadIdx.x;
        int v = (i < n) ? cnt[i] : 0;
        smem[threadIdx.x] = v;
        __syncthreads();
        for (int off = 1; off < 1024; off <<= 1) {
            int t = (threadIdx.x >= (unsigned)off) ? smem[threadIdx.x - off] : 0;
            __syncthreads();
            smem[threadIdx.x] += t;
            __syncthreads();
        }
        int incl = smem[threadIdx.x];
        if (i < n) {
            int ex = carry + incl - v;
            rowptr[i] = ex;
            cursor[i] = ex;
        }
        __syncthreads();
        if (threadIdx.x == 1023) carry += smem[1023];
        __syncthreads();
    }
    if (threadIdx.x == 0) rowptr[n] = carry;
}

__global__ void scatter_kernel(const int* __restrict__ src, int* __restrict__ cursor,
                               int* __restrict__ eids, int n_edges) {
    int e = blockIdx.x * blockDim.x + threadIdx.x;
    if (e >= n_edges) return;
    int p = atomicAdd(&cursor[src[e]], 1);
    eids[p] = e;
}

// ---------------------------------------------------------------------------
// PATH B node kernel: one wave per node, lane = feature. Gathers tangent rows
// via CSR, then expmap0 / mobius_add / projx with wave-shuffle reductions.
// ---------------------------------------------------------------------------
__device__ __forceinline__ float wred(float v) {
#pragma unroll
    for (int off = 32; off; off >>= 1) v += __shfl_xor(v, off, 64);
    return v;
}

__global__ void __launch_bounds__(256)
node_gather(const float* __restrict__ hV, const float* __restrict__ logc,
            const float* __restrict__ tg, const int* __restrict__ rowptr,
            const int* __restrict__ eids, float* __restrict__ out, int n_nodes) {
    int wid  = (blockIdx.x * blockDim.x + threadIdx.x) >> 6;
    int lane = threadIdx.x & 63;
    if (wid >= n_nodes) return;

    float c    = expf(logc[0]);
    float sc   = sqrtf(c);
    float maxn = (1.0f - 1e-5f) / sc;

    int beg = rowptr[wid], end = rowptr[wid + 1];
    float ssum = 0.f;
    for (int i = beg; i < end; ++i) {
        int e = eids[i];
        ssum += tg[(size_t)e * 64 + lane];
    }
    float inv = 1.f / fmaxf((float)(end - beg), 1.f);
    float at  = ssum * inv;

    float an2 = wred(at * at);
    float an  = sqrtf(an2);
    float ae  = tanhf(sc * an) / (an * sc + EPSF);   // expmap0 factor

    float xv  = hV[(size_t)wid * 64 + lane];
    float hs2 = wred(xv * xv);
    float sX  = fminf(maxn / fmaxf(sqrtf(hs2), EPSF), 1.0f);

    float x = sX * xv, y = ae * at;
    float x2 = wred(x * x);
    float y2 = wred(y * y);
    float xy = wred(x * y);

    float ca = 1.f + 2.f * c * xy + c * y2;
    float cb = 1.f - c * x2;
    float id = 1.f / (1.f + 2.f * c * xy + c * c * x2 * y2 + EPSF);

    float r   = (ca * x + cb * y) * id;
    float rn2 = wred(r * r);
    float rs  = fminf(maxn / fmaxf(sqrtf(rn2), EPSF), 1.0f);

    out[(size_t)wid * 64 + lane] = rs * r;
}

// ---------------------------------------------------------------------------
// PATH A node kernel: thread per node (reads atomically-built sums/counts).
// ---------------------------------------------------------------------------
__global__ void __launch_bounds__(256, 2)
node_kernel_a(const float* __restrict__ hV, const float* __restrict__ logc,
              const float* __restrict__ sums, const float* __restrict__ counts,
              float* __restrict__ out, int n_nodes) {
    int nd = blockIdx.x * blockDim.x + threadIdx.x;
    if (nd >= n_nodes) return;

    float c    = expf(logc[0]);
    float sc   = sqrtf(c);
    float maxn = (1.0f - 1e-5f) / sc;

    float inv = 1.0f / fmaxf(counts[nd], 1.0f);

    float at[64];
    float an2 = 0.f;
    const float4* sr = reinterpret_cast<const float4*>(sums) + (size_t)nd * 16;
#pragma unroll
    for (int q = 0; q < 16; ++q) {
        float4 a = sr[q];
        a.x *= inv; a.y *= inv; a.z *= inv; a.w *= inv;
        at[q * 4 + 0] = a.x; at[q * 4 + 1] = a.y;
        at[q * 4 + 2] = a.z; at[q * 4 + 3] = a.w;
        an2 += a.x * a.x + a.y * a.y + a.z * a.z + a.w * a.w;
    }
    float an = sqrtf(an2);
    float ae = tanhf(sc * an) / (an * sc + EPSF);

    float xv[64];
    float hs2 = 0.f;
    const float4* hr = reinterpret_cast<const float4*>(hV) + (size_t)nd * 16;
#pragma unroll
    for (int q = 0; q < 16; ++q) {
        float4 a = hr[q];
        xv[q * 4 + 0] = a.x; xv[q * 4 + 1] = a.y;
        xv[q * 4 + 2] = a.z; xv[q * 4 + 3] = a.w;
        hs2 += a.x * a.x + a.y * a.y + a.z * a.z + a.w * a.w;
    }
    float sX = fminf(maxn / fmaxf(sqrtf(hs2), EPSF), 1.0f);

    float x2 = 0.f, y2 = 0.f, xy = 0.f;
#pragma unroll
    for (int j = 0; j < 64; ++j) {
        float x = sX * xv[j];
        float y = ae * at[j];
        xv[j] = x; at[j] = y;
        x2 = fmaf(x, x, x2);
        y2 = fmaf(y, y, y2);
        xy = fmaf(x, y, xy);
    }

    float ca  = 1.f + 2.f * c * xy + c * y2;
    float cb  = 1.f - c * x2;
    float id  = 1.f / (1.f + 2.f * c * xy + c * c * x2 * y2 + EPSF);

    float rn2 = 0.f;
#pragma unroll
    for (int j = 0; j < 64; ++j) {
        float r = (ca * xv[j] + cb * at[j]) * id;
        xv[j] = r;
        rn2 = fmaf(r, r, rn2);
    }
    float rs = fminf(maxn / fmaxf(sqrtf(rn2), EPSF), 1.0f);

    float4* orow = reinterpret_cast<float4*>(out) + (size_t)nd * 16;
#pragma unroll
    for (int q = 0; q < 16; ++q) {
        float4 o;
        o.x = rs * xv[q * 4 + 0];
        o.y = rs * xv[q * 4 + 1];
        o.z = rs * xv[q * 4 + 2];
        o.w = rs * xv[q * 4 + 3];
        orow[q] = o;
    }
}

// ---------------------------------------------------------------------------
extern "C" void kernel_launch(void* const* d_in, const int* in_sizes, int n_in,
                              void* d_out, int out_size, void* d_ws, size_t ws_size,
                              hipStream_t stream) {
    const float* hV   = (const float*)d_in[0];
    const float* hE   = (const float*)d_in[1];
    const int*   src  = (const int*)d_in[2];
    const int*   dst  = (const int*)d_in[3];
    const float* logc = (const float*)d_in[4];
    const float* W1   = (const float*)d_in[5];
    const float* b1   = (const float*)d_in[6];
    const float* W2   = (const float*)d_in[7];
    const float* b2   = (const float*)d_in[8];
    const float* W3   = (const float*)d_in[9];
    const float* b3   = (const float*)d_in[10];

    int n_nodes = in_sizes[0] / 64;
    int n_edges = in_sizes[2];
    float* out = (float*)d_out;

    float* ws  = (float*)d_ws;
    float* W1t = ws;                 // 320*64
    float* W2t = W1t + 320 * 64;     // 64*64
    float* W3t = W2t + 64 * 64;      // 64*64
    size_t woff = 320 * 64 + 2 * 64 * 64;   // 28672 floats

    // Path-B layout
    int* cnt    = (int*)(ws + woff);
    int* rowptr = cnt + n_nodes;
    int* cursor = rowptr + n_nodes + 1;
    int* eids   = cursor + n_nodes;
    size_t tg_off = woff + (size_t)3 * n_nodes + 1 + n_edges;
    tg_off = (tg_off + 3) & ~(size_t)3;          // 16B align for float4
    float* tg = ws + tg_off;
    size_t need_b = (tg_off + (size_t)n_edges * 64) * sizeof(float);

    prep_kernel<<<(320 * 64 + 8192 + 255) / 256, 256, 0, stream>>>(W1, W2, W3, W1t, W2t, W3t);

    if (ws_size >= need_b) {
        // ---- PATH B: streaming tangent + CSR gather (no float atomics) ----
        hipMemsetAsync(cnt, 0, (size_t)n_nodes * sizeof(int), stream);
        edge_compute_b<<<(n_edges + 63) / 64, 64, 0, stream>>>(
            hV, hE, src, dst, logc, W1t, b1, W2t, b2, W3t, b3, tg, cnt, n_edges);
        scan_kernel<<<1, 1024, 0, stream>>>(cnt, rowptr, cursor, n_nodes);
        scatter_kernel<<<(n_edges + 255) / 256, 256, 0, stream>>>(src, cursor, eids, n_edges);
        node_gather<<<(n_nodes + 3) / 4, 256, 0, stream>>>(
            hV, logc, tg, rowptr, eids, out, n_nodes);
    } else {
        // ---- PATH A: coalesced atomic scatter fallback ----
        float* sums   = ws + woff;
        float* counts = sums + (size_t)n_nodes * 64;
        hipMemsetAsync(sums, 0, ((size_t)n_nodes * 64 + n_nodes) * sizeof(float), stream);
        edge_compute_a<<<(n_edges + 63) / 64, 64, 0, stream>>>(
            hV, hE, src, dst, logc, W1t, b1, W2t, b2, W3t, b3, sums, counts, n_edges);
        node_kernel_a<<<(n_nodes + 255) / 256, 256, 0, stream>>>(
            hV, logc, sums, counts, out, n_nodes);
    }
}

// Round 4
// 353.000 us; speedup vs baseline: 5.1518x; 2.4639x over previous
//
#include <hip/hip_runtime.h>
#include <math.h>

#define EPSF 1e-15f

typedef __attribute__((ext_vector_type(8))) short bf16x8;
typedef __attribute__((ext_vector_type(4))) float f32x4;

__device__ __forceinline__ unsigned short f2bf(float x) {
    unsigned u = __float_as_uint(x);
    u += 0x7fffu + ((u >> 16) & 1u);
    return (unsigned short)(u >> 16);
}
__device__ __forceinline__ float bf2f(unsigned short b) {
    return __uint_as_float(((unsigned)b) << 16);
}
// tanh(x) for x>=0; exact identity form + small-x polynomial (avoids 1-(1-x) cancellation)
__device__ __forceinline__ float fast_tanh_pos(float x) {
    if (x < 0.25f) { float x2 = x * x; return x * (1.0f - x2 * (0.33333334f - 0.13333334f * x2)); }
    float e = __expf(2.0f * x);
    return 1.0f - 2.0f / (e + 1.0f);
}
// atanh(y) for 0<=y<=1-1e-5
__device__ __forceinline__ float fast_atanh01(float y) {
    if (y < 0.125f) { float y2 = y * y; return y * (1.0f + y2 * (0.33333334f + 0.2f * y2)); }
    return 0.5f * __logf((1.0f + y) / (1.0f - y));
}

// ---------------------------------------------------------------------------
// prep: weight fragments in MFMA B-operand order, bf16.
// frag fid: 0..39 = W1 (ks=fid>>2 of 10, t=fid&3), 40..47 = W2, 48..55 = W3.
// B[k][n] = W[n][k] (out = t @ W.T). lane: n = t*16+(lane&15), k = ks*32+(lane>>4)*8+i
// ---------------------------------------------------------------------------
__global__ void prep_wfrag(const float* __restrict__ W1, const float* __restrict__ W2,
                           const float* __restrict__ W3, unsigned short* __restrict__ Wf) {
    int idx = blockIdx.x * blockDim.x + threadIdx.x;
    if (idx >= 56 * 64) return;
    int fid = idx >> 6, lane = idx & 63;
    int i15 = lane & 15, grp = lane >> 4;
    const float* srcW; int ks, t, ld;
    if (fid < 40)      { srcW = W1; ks = fid >> 2;        t = fid & 3; ld = 320; }
    else if (fid < 48) { srcW = W2; ks = (fid - 40) >> 2; t = fid & 3; ld = 64; }
    else               { srcW = W3; ks = (fid - 48) >> 2; t = fid & 3; ld = 64; }
    int col = t * 16 + i15;
    int k0  = ks * 32 + grp * 8;
    unsigned short* dstp = Wf + ((size_t)fid * 64 + lane) * 8;
#pragma unroll
    for (int i = 0; i < 8; ++i) dstp[i] = f2bf(srcW[col * ld + k0 + i]);
}

// ---------------------------------------------------------------------------
// one mobius "stage": v (C-layout [ntile][reg]) -> factors -> LDS transpose ->
// MFMA with W-frags -> v updated.  Wave-local (no __syncthreads).
// ---------------------------------------------------------------------------
__device__ __forceinline__ void stage_mlp(float (&v)[4][4], unsigned short* tb,
                                          const bf16x8* __restrict__ Wfrag, int fbase,
                                          const float* __restrict__ bvec,
                                          float scq, float maxn, int lane) {
    int i15 = lane & 15, grp = lane >> 4;
    float n2[4], rn2[4];
#pragma unroll
    for (int r = 0; r < 4; ++r) {
        float s = 0.f;
#pragma unroll
        for (int t = 0; t < 4; ++t) s = fmaf(v[t][r], v[t][r], s);
        n2[r] = s;
    }
    // u = relu(v): write bf16 to swizzled LDS, accumulate sum(u^2)
#pragma unroll
    for (int r = 0; r < 4; ++r) {
        float s = 0.f;
        int row = grp * 4 + r;
#pragma unroll
        for (int t = 0; t < 4; ++t) {
            float u = fmaxf(v[t][r], 0.f);
            s = fmaf(u, u, s);
            int colc = t * 16 + i15;
            int unit = (colc >> 3) ^ (row & 7);
            tb[row * 64 + unit * 8 + (colc & 7)] = f2bf(u);
        }
        rn2[r] = s;
    }
#pragma unroll
    for (int m = 1; m <= 8; m <<= 1) {
#pragma unroll
        for (int r = 0; r < 4; ++r) {
            n2[r]  += __shfl_xor(n2[r], m);
            rn2[r] += __shfl_xor(rn2[r], m);
        }
    }
    float f2[4];
#pragma unroll
    for (int r = 0; r < 4; ++r) {
        float n  = sqrtf(n2[r]);
        float h  = fast_tanh_pos(scq * n) / (n * scq + EPSF);   // expmap0 factor
        float rn = h * sqrtf(rn2[r]);                            // ||relu row|| after expmap
        float ps = fminf(maxn / fmaxf(rn, EPSF), 1.0f);
        float pn = rn * ps;
        float g  = fast_atanh01(fminf(scq * pn, 1.0f - 1e-5f)) / (scq * (pn + EPSF));
        f2[r] = h * ps * g;                                      // folded he*projx*logmap factor
    }
    asm volatile("s_waitcnt lgkmcnt(0)" ::: "memory");
    __builtin_amdgcn_sched_barrier(0);
    f32x4 acc[4] = {};
#pragma unroll
    for (int s2 = 0; s2 < 2; ++s2) {
        int unit = (s2 * 4 + grp) ^ (i15 & 7);
        bf16x8 a2 = *reinterpret_cast<const bf16x8*>(&tb[i15 * 64 + unit * 8]);
#pragma unroll
        for (int t = 0; t < 4; ++t)
            acc[t] = __builtin_amdgcn_mfma_f32_16x16x32_bf16(
                a2, Wfrag[(size_t)(fbase + s2 * 4 + t) * 64 + lane], acc[t], 0, 0, 0);
    }
#pragma unroll
    for (int t = 0; t < 4; ++t) {
        float bv = bvec[t * 16 + i15];
#pragma unroll
        for (int r = 0; r < 4; ++r) v[t][r] = fmaf(f2[r], acc[t][r], bv);
    }
}

// ---------------------------------------------------------------------------
// edge kernel: wave = 16 edges. MFMA chain, tangent rows -> tg (bf16).
// ---------------------------------------------------------------------------
__global__ void __launch_bounds__(256)
edge_mfma(const float* __restrict__ hV, const float* __restrict__ hE,
          const int* __restrict__ src, const int* __restrict__ dst,
          const float* __restrict__ logc, const unsigned short* __restrict__ Wf,
          const float* __restrict__ b1, const float* __restrict__ b2,
          const float* __restrict__ b3,
          unsigned short* __restrict__ tg, int* __restrict__ cnt, int n_edges) {
    __shared__ unsigned short tbuf[4][16 * 64];
    __shared__ float fbuf[4][16 * 68];
    int lane = threadIdx.x & 63;
    int w    = threadIdx.x >> 6;
    int tile = blockIdx.x * 4 + w;
    int e0 = tile * 16;
    if (e0 >= n_edges) return;

    float c    = __expf(logc[0]);
    float scq  = sqrtf(c);
    float maxn = (1.0f - 1e-5f) / scq;

    int i15 = lane & 15, grp = lane >> 4;
    int ev = e0 + i15; if (ev >= n_edges) ev = n_edges - 1;
    int s16 = src[ev], d16 = dst[ev];
    if (lane < 16 && e0 + lane < n_edges) atomicAdd(&cnt[s16], 1);

    const bf16x8* Wfrag = reinterpret_cast<const bf16x8*>(Wf);

    // ---- node segments: stage f32, norms, projx scale, cvt frags ----
    float sA[16], sB[16];
    float pS = 0.f, pD = 0.f;
    {
        const float4* ps4 = reinterpret_cast<const float4*>(hV + (size_t)s16 * 64);
        const float4* pd4 = reinterpret_cast<const float4*>(hV + (size_t)d16 * 64);
#pragma unroll
        for (int k2 = 0; k2 < 2; ++k2) {
            int fo = k2 * 8 + grp * 2;
            float4 a0 = ps4[fo], a1 = ps4[fo + 1];
            sA[k2*8+0]=a0.x; sA[k2*8+1]=a0.y; sA[k2*8+2]=a0.z; sA[k2*8+3]=a0.w;
            sA[k2*8+4]=a1.x; sA[k2*8+5]=a1.y; sA[k2*8+6]=a1.z; sA[k2*8+7]=a1.w;
            pS += a0.x*a0.x + a0.y*a0.y + a0.z*a0.z + a0.w*a0.w
                + a1.x*a1.x + a1.y*a1.y + a1.z*a1.z + a1.w*a1.w;
            float4 c0 = pd4[fo], c1 = pd4[fo + 1];
            sB[k2*8+0]=c0.x; sB[k2*8+1]=c0.y; sB[k2*8+2]=c0.z; sB[k2*8+3]=c0.w;
            sB[k2*8+4]=c1.x; sB[k2*8+5]=c1.y; sB[k2*8+6]=c1.z; sB[k2*8+7]=c1.w;
            pD += c0.x*c0.x + c0.y*c0.y + c0.z*c0.z + c0.w*c0.w
                + c1.x*c1.x + c1.y*c1.y + c1.z*c1.z + c1.w*c1.w;
        }
    }
    pS += __shfl_xor(pS, 16); pS += __shfl_xor(pS, 32);
    pD += __shfl_xor(pD, 16); pD += __shfl_xor(pD, 32);
    float sS = fminf(maxn / fmaxf(sqrtf(pS), EPSF), 1.0f);
    float sD = fminf(maxn / fmaxf(sqrtf(pD), EPSF), 1.0f);
    float pjS = sS * sS * pS, pjD = sD * sD * pD;

    bf16x8 afr[10];
#pragma unroll
    for (int k2 = 0; k2 < 2; ++k2) {
        bf16x8 fa, fb;
#pragma unroll
        for (int i = 0; i < 8; ++i) {
            fa[i] = (short)f2bf(sA[k2 * 8 + i] * sS);
            fb[i] = (short)f2bf(sB[k2 * 8 + i] * sD);
        }
        afr[6 + k2] = fa; afr[8 + k2] = fb;
    }

    // ---- hE: stage f32 (transient), norm, scale by projx sE, cvt frags ----
    float es[48];
    float pE = 0.f;
    const float* eb = hE + (size_t)ev * 192;
#pragma unroll
    for (int ks = 0; ks < 6; ++ks) {
        const float4* p4 = reinterpret_cast<const float4*>(eb + ks * 32 + grp * 8);
        float4 a0 = p4[0], a1 = p4[1];
        es[ks*8+0]=a0.x; es[ks*8+1]=a0.y; es[ks*8+2]=a0.z; es[ks*8+3]=a0.w;
        es[ks*8+4]=a1.x; es[ks*8+5]=a1.y; es[ks*8+6]=a1.z; es[ks*8+7]=a1.w;
        pE += a0.x*a0.x + a0.y*a0.y + a0.z*a0.z + a0.w*a0.w
            + a1.x*a1.x + a1.y*a1.y + a1.z*a1.z + a1.w*a1.w;
    }
    pE += __shfl_xor(pE, 16); pE += __shfl_xor(pE, 32);
    float sE = fminf(maxn / fmaxf(sqrtf(pE), EPSF), 1.0f);
#pragma unroll
    for (int ks = 0; ks < 6; ++ks) {
        bf16x8 f;
#pragma unroll
        for (int i = 0; i < 8; ++i) f[i] = (short)f2bf(es[ks * 8 + i] * sE);
        afr[ks] = f;
    }
    // logmap0 factor of the full projected 320-dim concat (per row = i15)
    float nt = sqrtf(sE * sE * pE + pjS + pjD);
    float gq = fast_atanh01(fminf(scq * nt, 1.0f - 1e-5f)) / (scq * (nt + EPSF));

    // ---- GEMM1: 10 K-steps x 4 N-tiles ----
    f32x4 acc[4] = {};
#pragma unroll
    for (int ks = 0; ks < 10; ++ks) {
#pragma unroll
        for (int t = 0; t < 4; ++t)
            acc[t] = __builtin_amdgcn_mfma_f32_16x16x32_bf16(
                afr[ks], Wfrag[(size_t)(ks * 4 + t) * 64 + lane], acc[t], 0, 0, 0);
    }

    // epilogue 1: v = g_row * acc + b1[col]
    float gr[4];
#pragma unroll
    for (int r = 0; r < 4; ++r) gr[r] = __shfl(gq, grp * 4 + r);
    float v[4][4];
#pragma unroll
    for (int t = 0; t < 4; ++t) {
        float bv = b1[t * 16 + i15];
#pragma unroll
        for (int r = 0; r < 4; ++r) v[t][r] = fmaf(gr[r], acc[t][r], bv);
    }

    // layers 2 and 3
    stage_mlp(v, tbuf[w], Wfrag, 40, b2, scq, maxn, lane);
    stage_mlp(v, tbuf[w], Wfrag, 48, b3, scq, maxn, lane);

    // tangent = logmap0(expmap0(v3)); factor per row
    float n2f[4];
#pragma unroll
    for (int r = 0; r < 4; ++r) {
        float s = 0.f;
#pragma unroll
        for (int t = 0; t < 4; ++t) s = fmaf(v[t][r], v[t][r], s);
        n2f[r] = s;
    }
#pragma unroll
    for (int m = 1; m <= 8; m <<= 1) {
#pragma unroll
        for (int r = 0; r < 4; ++r) n2f[r] += __shfl_xor(n2f[r], m);
    }
    float fT[4];
#pragma unroll
    for (int r = 0; r < 4; ++r) {
        float n  = sqrtf(n2f[r]);
        float h  = fast_tanh_pos(scq * n) / (n * scq + EPSF);
        float hn = h * n;
        float g4 = fast_atanh01(fminf(scq * hn, 1.0f - 1e-5f)) / (scq * (hn + EPSF));
        fT[r] = g4 * h;
    }
    // write f32 tangent to LDS, transpose, store bf16 rows coalesced
    float* fb = fbuf[w];
#pragma unroll
    for (int r = 0; r < 4; ++r) {
        int row = grp * 4 + r;
#pragma unroll
        for (int t = 0; t < 4; ++t) fb[row * 68 + t * 16 + i15] = fT[r] * v[t][r];
    }
    asm volatile("s_waitcnt lgkmcnt(0)" ::: "memory");
    __builtin_amdgcn_sched_barrier(0);
    int rowo = lane >> 2, cho = lane & 3;
    int eo = e0 + rowo;
    if (eo < n_edges) {
        float vals[16];
#pragma unroll
        for (int q = 0; q < 4; ++q) {
            f32x4 x = *reinterpret_cast<const f32x4*>(&fb[rowo * 68 + cho * 16 + q * 4]);
            vals[q*4+0] = x[0]; vals[q*4+1] = x[1]; vals[q*4+2] = x[2]; vals[q*4+3] = x[3];
        }
        unsigned pk[8];
#pragma unroll
        for (int i = 0; i < 8; ++i)
            pk[i] = (unsigned)f2bf(vals[2*i]) | ((unsigned)f2bf(vals[2*i+1]) << 16);
        uint4* op = reinterpret_cast<uint4*>(&tg[(size_t)eo * 64 + cho * 16]);
        op[0] = make_uint4(pk[0], pk[1], pk[2], pk[3]);
        op[1] = make_uint4(pk[4], pk[5], pk[6], pk[7]);
    }
}

// ---------------------------------------------------------------------------
// CSR build (unchanged from R3) + gather node kernel (tg now bf16)
// ---------------------------------------------------------------------------
__global__ void scan_kernel(const int* __restrict__ cnt, int* __restrict__ rowptr,
                            int* __restrict__ cursor, int n) {
    __shared__ int smem[1024];
    __shared__ int carry;
    if (threadIdx.x == 0) carry = 0;
    __syncthreads();
    for (int base = 0; base < n; base += 1024) {
        int i = base + (int)threadIdx.x;
        int v = (i < n) ? cnt[i] : 0;
        smem[threadIdx.x] = v;
        __syncthreads();
        for (int off = 1; off < 1024; off <<= 1) {
            int t = (threadIdx.x >= (unsigned)off) ? smem[threadIdx.x - off] : 0;
            __syncthreads();
            smem[threadIdx.x] += t;
            __syncthreads();
        }
        int incl = smem[threadIdx.x];
        if (i < n) {
            int ex = carry + incl - v;
            rowptr[i] = ex;
            cursor[i] = ex;
        }
        __syncthreads();
        if (threadIdx.x == 1023) carry += smem[1023];
        __syncthreads();
    }
    if (threadIdx.x == 0) rowptr[n] = carry;
}

__global__ void scatter_kernel(const int* __restrict__ src, int* __restrict__ cursor,
                               int* __restrict__ eids, int n_edges) {
    int e = blockIdx.x * blockDim.x + threadIdx.x;
    if (e >= n_edges) return;
    int p = atomicAdd(&cursor[src[e]], 1);
    eids[p] = e;
}

__device__ __forceinline__ float wred(float v) {
#pragma unroll
    for (int off = 32; off; off >>= 1) v += __shfl_xor(v, off);
    return v;
}

__global__ void __launch_bounds__(256)
node_gather(const float* __restrict__ hV, const float* __restrict__ logc,
            const unsigned short* __restrict__ tg, const int* __restrict__ rowptr,
            const int* __restrict__ eids, float* __restrict__ out, int n_nodes) {
    int wid  = (blockIdx.x * blockDim.x + threadIdx.x) >> 6;
    int lane = threadIdx.x & 63;
    if (wid >= n_nodes) return;

    float c    = __expf(logc[0]);
    float scq  = sqrtf(c);
    float maxn = (1.0f - 1e-5f) / scq;

    int beg = rowptr[wid], end = rowptr[wid + 1];
    float ssum = 0.f;
    for (int i = beg; i < end; ++i) {
        int e = eids[i];
        ssum += bf2f(tg[(size_t)e * 64 + lane]);
    }
    float inv = 1.f / fmaxf((float)(end - beg), 1.f);
    float at  = ssum * inv;

    float an2 = wred(at * at);
    float an  = sqrtf(an2);
    float ae  = fast_tanh_pos(scq * an) / (an * scq + EPSF);

    float xv  = hV[(size_t)wid * 64 + lane];
    float hs2 = wred(xv * xv);
    float sX  = fminf(maxn / fmaxf(sqrtf(hs2), EPSF), 1.0f);

    float x = sX * xv, y = ae * at;
    float x2 = wred(x * x);
    float y2 = wred(y * y);
    float xy = wred(x * y);

    float ca = 1.f + 2.f * c * xy + c * y2;
    float cb = 1.f - c * x2;
    float id = 1.f / (1.f + 2.f * c * xy + c * c * x2 * y2 + EPSF);

    float r   = (ca * x + cb * y) * id;
    float rn2 = wred(r * r);
    float rs  = fminf(maxn / fmaxf(sqrtf(rn2), EPSF), 1.0f);

    out[(size_t)wid * 64 + lane] = rs * r;
}

// ---------------------------------------------------------------------------
extern "C" void kernel_launch(void* const* d_in, const int* in_sizes, int n_in,
                              void* d_out, int out_size, void* d_ws, size_t ws_size,
                              hipStream_t stream) {
    const float* hV   = (const float*)d_in[0];
    const float* hE   = (const float*)d_in[1];
    const int*   src  = (const int*)d_in[2];
    const int*   dst  = (const int*)d_in[3];
    const float* logc = (const float*)d_in[4];
    const float* W1   = (const float*)d_in[5];
    const float* b1   = (const float*)d_in[6];
    const float* W2   = (const float*)d_in[7];
    const float* b2   = (const float*)d_in[8];
    const float* W3   = (const float*)d_in[9];
    const float* b3   = (const float*)d_in[10];

    int n_nodes = in_sizes[0] / 64;
    int n_edges = in_sizes[2];
    float* out = (float*)d_out;

    char* wsb = (char*)d_ws;
    unsigned short* Wf = (unsigned short*)wsb;                 // 56*512 ushort = 57344 B
    size_t off = 56 * 512 * sizeof(unsigned short);
    int* cnt    = (int*)(wsb + off);   off += (size_t)n_nodes * 4;
    int* rowptr = (int*)(wsb + off);   off += (size_t)(n_nodes + 1) * 4;
    int* cursor = (int*)(wsb + off);   off += (size_t)n_nodes * 4;
    int* eids   = (int*)(wsb + off);   off += (size_t)n_edges * 4;
    off = (off + 15) & ~(size_t)15;
    unsigned short* tg = (unsigned short*)(wsb + off);         // E*64 bf16

    hipMemsetAsync(cnt, 0, (size_t)n_nodes * sizeof(int), stream);

    prep_wfrag<<<(56 * 64 + 255) / 256, 256, 0, stream>>>(W1, W2, W3, Wf);

    int tiles = (n_edges + 15) / 16;
    edge_mfma<<<(tiles + 3) / 4, 256, 0, stream>>>(
        hV, hE, src, dst, logc, Wf, b1, b2, b3, tg, cnt, n_edges);

    scan_kernel<<<1, 1024, 0, stream>>>(cnt, rowptr, cursor, n_nodes);
    scatter_kernel<<<(n_edges + 255) / 256, 256, 0, stream>>>(src, cursor, eids, n_edges);
    node_gather<<<(n_nodes * 64 + 255) / 256, 256, 0, stream>>>(
        hV, logc, tg, rowptr, eids, out, n_nodes);
}

// Round 5
// 267.166 us; speedup vs baseline: 6.8069x; 1.3213x over previous
//
#include <hip/hip_runtime.h>
#include <hip/hip_bf16.h>
#include <math.h>

#define EPSF 1e-15f

typedef __attribute__((ext_vector_type(8))) short bf16x8;
typedef __attribute__((ext_vector_type(4))) float f32x4;

__device__ __forceinline__ unsigned short f2bf(float x) {
    unsigned u = __float_as_uint(x);
    u += 0x7fffu + ((u >> 16) & 1u);
    return (unsigned short)(u >> 16);
}
__device__ __forceinline__ float bf2f(unsigned short b) {
    return __uint_as_float(((unsigned)b) << 16);
}
__device__ __forceinline__ unsigned pkbf(float lo, float hi) {
    __hip_bfloat162 h = __float22bfloat162_rn(make_float2(lo, hi));
    return *reinterpret_cast<unsigned*>(&h);
}
// tanh(x) for x>=0; identity form + small-x polynomial
__device__ __forceinline__ float fast_tanh_pos(float x) {
    if (x < 0.25f) { float x2 = x * x; return x * (1.0f - x2 * (0.33333334f - 0.13333334f * x2)); }
    float e = __expf(2.0f * x);
    return 1.0f - 2.0f / (e + 1.0f);
}
// atanh(y) for 0<=y<=1-1e-5
__device__ __forceinline__ float fast_atanh01(float y) {
    if (y < 0.125f) { float y2 = y * y; return y * (1.0f + y2 * (0.33333334f + 0.2f * y2)); }
    return 0.5f * __logf((1.0f + y) / (1.0f - y));
}

__device__ __forceinline__ float wred(float v) {
#pragma unroll
    for (int off = 32; off; off >>= 1) v += __shfl_xor(v, off);
    return v;
}

// ---------------------------------------------------------------------------
// prep: weight fragments in MFMA B-operand order, bf16 (unchanged from R4).
// ---------------------------------------------------------------------------
__global__ void prep_wfrag(const float* __restrict__ W1, const float* __restrict__ W2,
                           const float* __restrict__ W3, unsigned short* __restrict__ Wf) {
    int idx = blockIdx.x * blockDim.x + threadIdx.x;
    if (idx >= 56 * 64) return;
    int fid = idx >> 6, lane = idx & 63;
    int i15 = lane & 15, grp = lane >> 4;
    const float* srcW; int ks, t, ld;
    if (fid < 40)      { srcW = W1; ks = fid >> 2;        t = fid & 3; ld = 320; }
    else if (fid < 48) { srcW = W2; ks = (fid - 40) >> 2; t = fid & 3; ld = 64; }
    else               { srcW = W3; ks = (fid - 48) >> 2; t = fid & 3; ld = 64; }
    int col = t * 16 + i15;
    int k0  = ks * 32 + grp * 8;
    unsigned short* dstp = Wf + ((size_t)fid * 64 + lane) * 8;
#pragma unroll
    for (int i = 0; i < 8; ++i) dstp[i] = f2bf(srcW[col * ld + k0 + i]);
}

// ---------------------------------------------------------------------------
// node precompute: hVp = bf16 projx-scaled node rows, pj = ||projx(hV_n)||^2.
// Removes per-edge recompute of node norms/scales (was done ~32x per node).
// ---------------------------------------------------------------------------
__global__ void __launch_bounds__(256)
node_prep(const float* __restrict__ hV, const float* __restrict__ logc,
          unsigned short* __restrict__ hVp, float* __restrict__ pj, int n_nodes) {
    int wid  = (blockIdx.x * blockDim.x + threadIdx.x) >> 6;
    int lane = threadIdx.x & 63;
    if (wid >= n_nodes) return;
    float c    = __expf(logc[0]);
    float scq  = sqrtf(c);
    float maxn = (1.0f - 1e-5f) / scq;
    float x = hV[(size_t)wid * 64 + lane];
    float p = wred(x * x);
    float sS = fminf(maxn / fmaxf(sqrtf(p), EPSF), 1.0f);
    hVp[(size_t)wid * 64 + lane] = f2bf(x * sS);
    if (lane == 0) pj[wid] = sS * sS * p;
}

// ---------------------------------------------------------------------------
// CSR slot assignment: myoff via atomic histogram, then block-scan, then fix.
// ---------------------------------------------------------------------------
__global__ void hist_kernel(const int* __restrict__ src, int* __restrict__ cnt,
                            int* __restrict__ slot, int n_edges) {
    int e = blockIdx.x * blockDim.x + threadIdx.x;
    if (e < n_edges) slot[e] = atomicAdd(&cnt[src[e]], 1);
}

__global__ void __launch_bounds__(1024)
scan_rowptr(const int* __restrict__ cnt, int* __restrict__ rowptr, int n) {
    __shared__ int wpart[16];
    int C   = (n + 1023) >> 10;
    int tid = threadIdx.x;
    int beg = tid * C;
    int end = beg + C; if (end > n) end = n;
    int s = 0;
    if (beg < n) for (int k = beg; k < end; ++k) s += cnt[k];
    int lane = tid & 63, wv = tid >> 6;
    int v = s;
#pragma unroll
    for (int off = 1; off < 64; off <<= 1) {
        int t = __shfl_up(v, off);
        if (lane >= off) v += t;
    }
    if (lane == 63) wpart[wv] = v;
    __syncthreads();
    if (tid < 64) {
        int t = (tid < 16) ? wpart[tid] : 0;
#pragma unroll
        for (int off = 1; off < 16; off <<= 1) {
            int u = __shfl_up(t, off);
            if (lane >= off) t += u;
        }
        if (tid < 16) wpart[tid] = t;
    }
    __syncthreads();
    int base = (wv ? wpart[wv - 1] : 0) + (v - s);
    if (beg < n) {
        int run = base;
        for (int k = beg; k < end; ++k) { rowptr[k] = run; run += cnt[k]; }
    }
    if (tid == 1023) rowptr[n] = wpart[15];
}

__global__ void slotfix_kernel(const int* __restrict__ src, const int* __restrict__ rowptr,
                               int* __restrict__ slot, int n_edges) {
    int e = blockIdx.x * blockDim.x + threadIdx.x;
    if (e < n_edges) slot[e] += rowptr[src[e]];
}

// ---------------------------------------------------------------------------
// one mobius "stage" (proven R4 code): v -> factors -> LDS transpose -> MFMA.
// ---------------------------------------------------------------------------
__device__ __forceinline__ void stage_mlp(float (&v)[4][4], unsigned short* tb,
                                          const bf16x8* __restrict__ Wfrag, int fbase,
                                          const float* __restrict__ bvec,
                                          float scq, float maxn, int lane) {
    int i15 = lane & 15, grp = lane >> 4;
    float n2[4], rn2[4];
#pragma unroll
    for (int r = 0; r < 4; ++r) {
        float s = 0.f;
#pragma unroll
        for (int t = 0; t < 4; ++t) s = fmaf(v[t][r], v[t][r], s);
        n2[r] = s;
    }
#pragma unroll
    for (int r = 0; r < 4; ++r) {
        float s = 0.f;
        int row = grp * 4 + r;
#pragma unroll
        for (int t = 0; t < 4; ++t) {
            float u = fmaxf(v[t][r], 0.f);
            s = fmaf(u, u, s);
            int colc = t * 16 + i15;
            int unit = (colc >> 3) ^ (row & 7);
            tb[row * 64 + unit * 8 + (colc & 7)] = f2bf(u);
        }
        rn2[r] = s;
    }
#pragma unroll
    for (int m = 1; m <= 8; m <<= 1) {
#pragma unroll
        for (int r = 0; r < 4; ++r) {
            n2[r]  += __shfl_xor(n2[r], m);
            rn2[r] += __shfl_xor(rn2[r], m);
        }
    }
    float f2[4];
#pragma unroll
    for (int r = 0; r < 4; ++r) {
        float n  = sqrtf(n2[r]);
        float h  = fast_tanh_pos(scq * n) / (n * scq + EPSF);
        float rn = h * sqrtf(rn2[r]);
        float ps = fminf(maxn / fmaxf(rn, EPSF), 1.0f);
        float pn = rn * ps;
        float g  = fast_atanh01(fminf(scq * pn, 1.0f - 1e-5f)) / (scq * (pn + EPSF));
        f2[r] = h * ps * g;
    }
    asm volatile("s_waitcnt lgkmcnt(0)" ::: "memory");
    __builtin_amdgcn_sched_barrier(0);
    f32x4 acc[4] = {};
#pragma unroll
    for (int s2 = 0; s2 < 2; ++s2) {
        int unit = (s2 * 4 + grp) ^ (i15 & 7);
        bf16x8 a2 = *reinterpret_cast<const bf16x8*>(&tb[i15 * 64 + unit * 8]);
#pragma unroll
        for (int t = 0; t < 4; ++t)
            acc[t] = __builtin_amdgcn_mfma_f32_16x16x32_bf16(
                a2, Wfrag[(size_t)(fbase + s2 * 4 + t) * 64 + lane], acc[t], 0, 0, 0);
    }
#pragma unroll
    for (int t = 0; t < 4; ++t) {
        float bv = bvec[t * 16 + i15];
#pragma unroll
        for (int r = 0; r < 4; ++r) v[t][r] = fmaf(f2[r], acc[t][r], bv);
    }
}

// ---------------------------------------------------------------------------
// edge kernel: wave = 16 edges. Split accumulators (accE/accV) so hE converts
// unscaled immediately (no dependence on the sE reduce); node frags gathered
// pre-projected bf16; tangent written to CSR slot (coalesced node_gather).
// ---------------------------------------------------------------------------
__global__ void __launch_bounds__(256)
edge_mfma(const float* __restrict__ hE, const int* __restrict__ src,
          const int* __restrict__ dst, const float* __restrict__ logc,
          const unsigned short* __restrict__ Wf, const unsigned short* __restrict__ hVp,
          const float* __restrict__ pj,
          const float* __restrict__ b1, const float* __restrict__ b2,
          const float* __restrict__ b3, const int* __restrict__ slot,
          unsigned short* __restrict__ tg, int n_edges) {
    // per-wave scratch: stage_mlp tile (2048B as ushort) and tangent
    // transpose tile (16x68 f32 = 4352B) time-share one buffer.
    __shared__ __align__(16) float fbuf[4][16 * 68];
    int lane = threadIdx.x & 63;
    int w    = threadIdx.x >> 6;
    int tile = blockIdx.x * 4 + w;
    int e0 = tile * 16;
    if (e0 >= n_edges) return;

    float c    = __expf(logc[0]);
    float scq  = sqrtf(c);
    float maxn = (1.0f - 1e-5f) / scq;

    int i15 = lane & 15, grp = lane >> 4;
    int ev = e0 + i15; if (ev >= n_edges) ev = n_edges - 1;
    int s16 = src[ev], d16 = dst[ev];

    const bf16x8* Wfrag = reinterpret_cast<const bf16x8*>(Wf);

    // node fragments: direct bf16 gather (projx already folded at node level)
    const bf16x8* vsp = reinterpret_cast<const bf16x8*>(hVp + (size_t)s16 * 64);
    const bf16x8* vdp = reinterpret_cast<const bf16x8*>(hVp + (size_t)d16 * 64);
    bf16x8 aS0 = vsp[grp], aS1 = vsp[4 + grp];
    bf16x8 aD0 = vdp[grp], aD1 = vdp[4 + grp];
    float pjS = pj[s16], pjD = pj[d16];

    // hE: load, squares, convert unscaled bf16 immediately (frees the f32 regs)
    float pE = 0.f;
    bf16x8 aE[6];
    const float* eb = hE + (size_t)ev * 192;
#pragma unroll
    for (int ks = 0; ks < 6; ++ks) {
        const float4* p4 = reinterpret_cast<const float4*>(eb + ks * 32 + grp * 8);
        float4 a0 = p4[0], a1 = p4[1];
        pE += a0.x*a0.x + a0.y*a0.y + a0.z*a0.z + a0.w*a0.w
            + a1.x*a1.x + a1.y*a1.y + a1.z*a1.z + a1.w*a1.w;
        union { bf16x8 b; unsigned u[4]; } cv;
        cv.u[0] = pkbf(a0.x, a0.y);
        cv.u[1] = pkbf(a0.z, a0.w);
        cv.u[2] = pkbf(a1.x, a1.y);
        cv.u[3] = pkbf(a1.z, a1.w);
        aE[ks] = cv.b;
    }
    pE += __shfl_xor(pE, 16); pE += __shfl_xor(pE, 32);
    float sE = fminf(maxn / fmaxf(sqrtf(pE), EPSF), 1.0f);
    float nt = sqrtf(sE * sE * pE + pjS + pjD);
    float gq = fast_atanh01(fminf(scq * nt, 1.0f - 1e-5f)) / (scq * (nt + EPSF));

    // GEMM1: hE part (scale deferred) and node part (already scaled)
    f32x4 accE[4] = {}, accV[4] = {};
#pragma unroll
    for (int ks = 0; ks < 6; ++ks) {
#pragma unroll
        for (int t = 0; t < 4; ++t)
            accE[t] = __builtin_amdgcn_mfma_f32_16x16x32_bf16(
                aE[ks], Wfrag[(size_t)(ks * 4 + t) * 64 + lane], accE[t], 0, 0, 0);
    }
#pragma unroll
    for (int t = 0; t < 4; ++t)
        accV[t] = __builtin_amdgcn_mfma_f32_16x16x32_bf16(
            aS0, Wfrag[(size_t)(24 + t) * 64 + lane], accV[t], 0, 0, 0);
#pragma unroll
    for (int t = 0; t < 4; ++t)
        accV[t] = __builtin_amdgcn_mfma_f32_16x16x32_bf16(
            aS1, Wfrag[(size_t)(28 + t) * 64 + lane], accV[t], 0, 0, 0);
#pragma unroll
    for (int t = 0; t < 4; ++t)
        accV[t] = __builtin_amdgcn_mfma_f32_16x16x32_bf16(
            aD0, Wfrag[(size_t)(32 + t) * 64 + lane], accV[t], 0, 0, 0);
#pragma unroll
    for (int t = 0; t < 4; ++t)
        accV[t] = __builtin_amdgcn_mfma_f32_16x16x32_bf16(
            aD1, Wfrag[(size_t)(36 + t) * 64 + lane], accV[t], 0, 0, 0);

    // epilogue 1: v = g_row * (sE_row * accE + accV) + b1[col]
    float gr[4], ser[4];
#pragma unroll
    for (int r = 0; r < 4; ++r) {
        gr[r]  = __shfl(gq, grp * 4 + r);
        ser[r] = __shfl(sE, grp * 4 + r);
    }
    float v[4][4];
#pragma unroll
    for (int t = 0; t < 4; ++t) {
        float bv = b1[t * 16 + i15];
#pragma unroll
        for (int r = 0; r < 4; ++r)
            v[t][r] = fmaf(gr[r], fmaf(ser[r], accE[t][r], accV[t][r]), bv);
    }

    unsigned short* tb = reinterpret_cast<unsigned short*>(fbuf[w]);
    stage_mlp(v, tb, Wfrag, 40, b2, scq, maxn, lane);
    stage_mlp(v, tb, Wfrag, 48, b3, scq, maxn, lane);

    // tangent = logmap0(expmap0(v3)) factor per row
    float n2f[4];
#pragma unroll
    for (int r = 0; r < 4; ++r) {
        float s = 0.f;
#pragma unroll
        for (int t = 0; t < 4; ++t) s = fmaf(v[t][r], v[t][r], s);
        n2f[r] = s;
    }
#pragma unroll
    for (int m = 1; m <= 8; m <<= 1) {
#pragma unroll
        for (int r = 0; r < 4; ++r) n2f[r] += __shfl_xor(n2f[r], m);
    }
    float fT[4];
#pragma unroll
    for (int r = 0; r < 4; ++r) {
        float n  = sqrtf(n2f[r]);
        float h  = fast_tanh_pos(scq * n) / (n * scq + EPSF);
        float hn = h * n;
        float g4 = fast_atanh01(fminf(scq * hn, 1.0f - 1e-5f)) / (scq * (hn + EPSF));
        fT[r] = g4 * h;
    }
    // transpose via LDS (f32), store bf16 rows to CSR slot
    float* fb = fbuf[w];
    asm volatile("s_waitcnt lgkmcnt(0)" ::: "memory");   // stage_mlp reads done before overwrite
#pragma unroll
    for (int r = 0; r < 4; ++r) {
        int row = grp * 4 + r;
#pragma unroll
        for (int t = 0; t < 4; ++t) fb[row * 68 + t * 16 + i15] = fT[r] * v[t][r];
    }
    asm volatile("s_waitcnt lgkmcnt(0)" ::: "memory");
    __builtin_amdgcn_sched_barrier(0);
    int rowo = lane >> 2, cho = lane & 3;
    int eo = e0 + rowo;
    if (eo < n_edges) {
        int sl = slot[eo];
        float vals[16];
#pragma unroll
        for (int q = 0; q < 4; ++q) {
            f32x4 x = *reinterpret_cast<const f32x4*>(&fb[rowo * 68 + cho * 16 + q * 4]);
            vals[q*4+0] = x[0]; vals[q*4+1] = x[1]; vals[q*4+2] = x[2]; vals[q*4+3] = x[3];
        }
        unsigned pk[8];
#pragma unroll
        for (int i = 0; i < 8; ++i) pk[i] = pkbf(vals[2*i], vals[2*i+1]);
        uint4* op = reinterpret_cast<uint4*>(&tg[(size_t)sl * 64 + cho * 16]);
        op[0] = make_uint4(pk[0], pk[1], pk[2], pk[3]);
        op[1] = make_uint4(pk[4], pk[5], pk[6], pk[7]);
    }
}

// ---------------------------------------------------------------------------
// node kernel: contiguous CSR range -> mean -> expmap0 -> mobius_add -> projx
// ---------------------------------------------------------------------------
__global__ void __launch_bounds__(256)
node_gather(const float* __restrict__ hV, const float* __restrict__ logc,
            const unsigned short* __restrict__ tg, const int* __restrict__ rowptr,
            float* __restrict__ out, int n_nodes) {
    int wid  = (blockIdx.x * blockDim.x + threadIdx.x) >> 6;
    int lane = threadIdx.x & 63;
    if (wid >= n_nodes) return;

    float c    = __expf(logc[0]);
    float scq  = sqrtf(c);
    float maxn = (1.0f - 1e-5f) / scq;

    int beg = rowptr[wid], end = rowptr[wid + 1];
    float ssum = 0.f;
    for (int i = beg; i < end; ++i)
        ssum += bf2f(tg[(size_t)i * 64 + lane]);
    float inv = 1.f / fmaxf((float)(end - beg), 1.f);
    float at  = ssum * inv;

    float an2 = wred(at * at);
    float an  = sqrtf(an2);
    float ae  = fast_tanh_pos(scq * an) / (an * scq + EPSF);

    float xv  = hV[(size_t)wid * 64 + lane];
    float hs2 = wred(xv * xv);
    float sX  = fminf(maxn / fmaxf(sqrtf(hs2), EPSF), 1.0f);

    float x = sX * xv, y = ae * at;
    float x2 = wred(x * x);
    float y2 = wred(y * y);
    float xy = wred(x * y);

    float ca = 1.f + 2.f * c * xy + c * y2;
    float cb = 1.f - c * x2;
    float id = 1.f / (1.f + 2.f * c * xy + c * c * x2 * y2 + EPSF);

    float r   = (ca * x + cb * y) * id;
    float rn2 = wred(r * r);
    float rs  = fminf(maxn / fmaxf(sqrtf(rn2), EPSF), 1.0f);

    out[(size_t)wid * 64 + lane] = rs * r;
}

// ---------------------------------------------------------------------------
extern "C" void kernel_launch(void* const* d_in, const int* in_sizes, int n_in,
                              void* d_out, int out_size, void* d_ws, size_t ws_size,
                              hipStream_t stream) {
    const float* hV   = (const float*)d_in[0];
    const float* hE   = (const float*)d_in[1];
    const int*   src  = (const int*)d_in[2];
    const int*   dst  = (const int*)d_in[3];
    const float* logc = (const float*)d_in[4];
    const float* W1   = (const float*)d_in[5];
    const float* b1   = (const float*)d_in[6];
    const float* W2   = (const float*)d_in[7];
    const float* b2   = (const float*)d_in[8];
    const float* W3   = (const float*)d_in[9];
    const float* b3   = (const float*)d_in[10];

    int n_nodes = in_sizes[0] / 64;
    int n_edges = in_sizes[2];
    float* out = (float*)d_out;

    char* wsb = (char*)d_ws;
    unsigned short* Wf = (unsigned short*)wsb;                 // 56*512 ushort
    size_t off = 56 * 512 * sizeof(unsigned short);
    int* cnt    = (int*)(wsb + off);   off += (size_t)n_nodes * 4;
    int* rowptr = (int*)(wsb + off);   off += (size_t)(n_nodes + 1) * 4;
    int* slot   = (int*)(wsb + off);   off += (size_t)n_edges * 4;
    float* pj   = (float*)(wsb + off); off += (size_t)n_nodes * 4;
    off = (off + 15) & ~(size_t)15;
    unsigned short* hVp = (unsigned short*)(wsb + off);        // N*64 bf16
    off += (size_t)n_nodes * 64 * 2;
    off = (off + 15) & ~(size_t)15;
    unsigned short* tg = (unsigned short*)(wsb + off);         // E*64 bf16

    hipMemsetAsync(cnt, 0, (size_t)n_nodes * sizeof(int), stream);

    prep_wfrag<<<(56 * 64 + 255) / 256, 256, 0, stream>>>(W1, W2, W3, Wf);
    node_prep<<<(n_nodes + 3) / 4, 256, 0, stream>>>(hV, logc, hVp, pj, n_nodes);
    hist_kernel<<<(n_edges + 255) / 256, 256, 0, stream>>>(src, cnt, slot, n_edges);
    scan_rowptr<<<1, 1024, 0, stream>>>(cnt, rowptr, n_nodes);
    slotfix_kernel<<<(n_edges + 255) / 256, 256, 0, stream>>>(src, rowptr, slot, n_edges);

    int tiles = (n_edges + 15) / 16;
    edge_mfma<<<(tiles + 3) / 4, 256, 0, stream>>>(
        hE, src, dst, logc, Wf, hVp, pj, b1, b2, b3, slot, tg, n_edges);

    node_gather<<<(n_nodes + 3) / 4, 256, 0, stream>>>(
        hV, logc, tg, rowptr, out, n_nodes);
}

// Round 6
// 237.404 us; speedup vs baseline: 7.6602x; 1.1254x over previous
//
#include <hip/hip_runtime.h>
#include <hip/hip_bf16.h>
#include <math.h>

#define EPSF 1e-15f

typedef __attribute__((ext_vector_type(8))) short bf16x8;
typedef __attribute__((ext_vector_type(4))) float f32x4;

__device__ __forceinline__ unsigned short f2bf(float x) {
    unsigned u = __float_as_uint(x);
    u += 0x7fffu + ((u >> 16) & 1u);
    return (unsigned short)(u >> 16);
}
__device__ __forceinline__ float bf2f(unsigned short b) {
    return __uint_as_float(((unsigned)b) << 16);
}
__device__ __forceinline__ unsigned pkbf(float lo, float hi) {
    __hip_bfloat162 h = __float22bfloat162_rn(make_float2(lo, hi));
    return *reinterpret_cast<unsigned*>(&h);
}
// tanh(x) for x>=0; identity form + small-x polynomial
__device__ __forceinline__ float fast_tanh_pos(float x) {
    if (x < 0.25f) { float x2 = x * x; return x * (1.0f - x2 * (0.33333334f - 0.13333334f * x2)); }
    float e = __expf(2.0f * x);
    return 1.0f - 2.0f / (e + 1.0f);
}
// atanh(y) for 0<=y<=1-1e-5
__device__ __forceinline__ float fast_atanh01(float y) {
    if (y < 0.125f) { float y2 = y * y; return y * (1.0f + y2 * (0.33333334f + 0.2f * y2)); }
    return 0.5f * __logf((1.0f + y) / (1.0f - y));
}

__device__ __forceinline__ float wred(float v) {
#pragma unroll
    for (int off = 32; off; off >>= 1) v += __shfl_xor(v, off);
    return v;
}

// ---------------------------------------------------------------------------
// prep: weight fragments, bf16.
// fid 0..39 (W1, ks=fid>>2, t=fid&3): natural k order (A/B-frag layouts agree):
//   val(lane,i) = W1[16t + (lane&15)][32ks + 8*(lane>>4) + i]
// fid 40..55 (W2/W3, s2, t): k-PERMUTED so layer-2/3 B-frags are the previous
//   layer's register-resident C fragments (pi within each 32-k-step):
//   k_perm(i) = 16*(2*s2 + (i>>2)) + 4*(lane>>4) + (i&3)
// ---------------------------------------------------------------------------
__global__ void prep_wfrag(const float* __restrict__ W1, const float* __restrict__ W2,
                           const float* __restrict__ W3, unsigned short* __restrict__ Wf) {
    int idx = blockIdx.x * blockDim.x + threadIdx.x;
    if (idx >= 56 * 64) return;
    int fid = idx >> 6, lane = idx & 63;
    int i15 = lane & 15, grp = lane >> 4;
    unsigned short* dstp = Wf + ((size_t)fid * 64 + lane) * 8;
    if (fid < 40) {
        int ks = fid >> 2, t = fid & 3;
        int n = t * 16 + i15;
        int k0 = ks * 32 + grp * 8;
#pragma unroll
        for (int i = 0; i < 8; ++i) dstp[i] = f2bf(W1[n * 320 + k0 + i]);
    } else {
        const float* srcW = (fid < 48) ? W2 : W3;
        int b = (fid < 48) ? fid - 40 : fid - 48;
        int s2 = b >> 2, t = b & 3;
        int n = t * 16 + i15;
#pragma unroll
        for (int i = 0; i < 8; ++i) {
            int kp = 16 * (2 * s2 + (i >> 2)) + 4 * grp + (i & 3);
            dstp[i] = f2bf(srcW[n * 64 + kp]);
        }
    }
}

// ---------------------------------------------------------------------------
// node precompute: hVp = bf16 projx-scaled node rows, pj = ||projx(hV_n)||^2
// ---------------------------------------------------------------------------
__global__ void __launch_bounds__(256)
node_prep(const float* __restrict__ hV, const float* __restrict__ logc,
          unsigned short* __restrict__ hVp, float* __restrict__ pj, int n_nodes) {
    int wid  = (blockIdx.x * blockDim.x + threadIdx.x) >> 6;
    int lane = threadIdx.x & 63;
    if (wid >= n_nodes) return;
    float c    = __expf(logc[0]);
    float scq  = sqrtf(c);
    float maxn = (1.0f - 1e-5f) / scq;
    float x = hV[(size_t)wid * 64 + lane];
    float p = wred(x * x);
    float sS = fminf(maxn / fmaxf(sqrtf(p), EPSF), 1.0f);
    hVp[(size_t)wid * 64 + lane] = f2bf(x * sS);
    if (lane == 0) pj[wid] = sS * sS * p;
}

// ---------------------------------------------------------------------------
// CSR slot assignment: atomic histogram -> block scan -> slot fixup
// ---------------------------------------------------------------------------
__global__ void hist_kernel(const int* __restrict__ src, int* __restrict__ cnt,
                            int* __restrict__ slot, int n_edges) {
    int e = blockIdx.x * blockDim.x + threadIdx.x;
    if (e < n_edges) slot[e] = atomicAdd(&cnt[src[e]], 1);
}

__global__ void __launch_bounds__(1024)
scan_rowptr(const int* __restrict__ cnt, int* __restrict__ rowptr, int n) {
    __shared__ int wpart[16];
    int C   = (n + 1023) >> 10;
    int tid = threadIdx.x;
    int beg = tid * C;
    int end = beg + C; if (end > n) end = n;
    int s = 0;
    if (beg < n) for (int k = beg; k < end; ++k) s += cnt[k];
    int lane = tid & 63, wv = tid >> 6;
    int v = s;
#pragma unroll
    for (int off = 1; off < 64; off <<= 1) {
        int t = __shfl_up(v, off);
        if (lane >= off) v += t;
    }
    if (lane == 63) wpart[wv] = v;
    __syncthreads();
    if (tid < 64) {
        int t = (tid < 16) ? wpart[tid] : 0;
#pragma unroll
        for (int off = 1; off < 16; off <<= 1) {
            int u = __shfl_up(t, off);
            if (lane >= off) t += u;
        }
        if (tid < 16) wpart[tid] = t;
    }
    __syncthreads();
    int base = (wv ? wpart[wv - 1] : 0) + (v - s);
    if (beg < n) {
        int run = base;
        for (int k = beg; k < end; ++k) { rowptr[k] = run; run += cnt[k]; }
    }
    if (tid == 1023) rowptr[n] = wpart[15];
}

__global__ void slotfix_kernel(const int* __restrict__ src, const int* __restrict__ rowptr,
                               int* __restrict__ slot, int n_edges) {
    int e = blockIdx.x * blockDim.x + threadIdx.x;
    if (e < n_edges) slot[e] += rowptr[src[e]];
}

// ---------------------------------------------------------------------------
// transposed mobius stage: v (C^T layout: col=edge=lane&15, rows=feats) ->
// per-lane factors -> register B-frags (pi-permuted weights) -> MFMA.
// No LDS, no broadcasts, factor chain once per lane.
// ---------------------------------------------------------------------------
__device__ __forceinline__ void stage_mlp_t(float (&v)[4][4],
                                            const bf16x8* __restrict__ Wfrag, int fbase,
                                            const float* __restrict__ bvec,
                                            float scq, float maxn, int grp) {
    float n2 = 0.f, rn2 = 0.f;
    float u[4][4];
#pragma unroll
    for (int t = 0; t < 4; ++t)
#pragma unroll
        for (int r = 0; r < 4; ++r) {
            float x = v[t][r];
            n2 = fmaf(x, x, n2);
            float y = fmaxf(x, 0.f);
            u[t][r] = y;
            rn2 = fmaf(y, y, rn2);
        }
    n2  += __shfl_xor(n2, 16);  n2  += __shfl_xor(n2, 32);
    rn2 += __shfl_xor(rn2, 16); rn2 += __shfl_xor(rn2, 32);
    float n  = sqrtf(n2);
    float h  = fast_tanh_pos(scq * n) / (n * scq + EPSF);   // expmap0 factor
    float rn = h * sqrtf(rn2);
    float ps = fminf(maxn / fmaxf(rn, EPSF), 1.0f);
    float pn = rn * ps;
    float gg = fast_atanh01(fminf(scq * pn, 1.0f - 1e-5f)) / (scq * (pn + EPSF));
    float f2 = h * ps * gg;                                  // folded, post-applied

    union { bf16x8 b; unsigned w[4]; } B0, B1;
    B0.w[0] = pkbf(u[0][0], u[0][1]); B0.w[1] = pkbf(u[0][2], u[0][3]);
    B0.w[2] = pkbf(u[1][0], u[1][1]); B0.w[3] = pkbf(u[1][2], u[1][3]);
    B1.w[0] = pkbf(u[2][0], u[2][1]); B1.w[1] = pkbf(u[2][2], u[2][3]);
    B1.w[2] = pkbf(u[3][0], u[3][1]); B1.w[3] = pkbf(u[3][2], u[3][3]);

    f32x4 acc[4] = {};
#pragma unroll
    for (int t = 0; t < 4; ++t)
        acc[t] = __builtin_amdgcn_mfma_f32_16x16x32_bf16(
            Wfrag[(size_t)(fbase + t) * 64 + (grp * 16 + (threadIdx.x & 15))], B0.b, acc[t], 0, 0, 0);
#pragma unroll
    for (int t = 0; t < 4; ++t)
        acc[t] = __builtin_amdgcn_mfma_f32_16x16x32_bf16(
            Wfrag[(size_t)(fbase + 4 + t) * 64 + (grp * 16 + (threadIdx.x & 15))], B1.b, acc[t], 0, 0, 0);

#pragma unroll
    for (int t = 0; t < 4; ++t) {
        const float4 bv = *reinterpret_cast<const float4*>(&bvec[t * 16 + 4 * grp]);
        v[t][0] = fmaf(f2, acc[t][0], bv.x);
        v[t][1] = fmaf(f2, acc[t][1], bv.y);
        v[t][2] = fmaf(f2, acc[t][2], bv.z);
        v[t][3] = fmaf(f2, acc[t][3], bv.w);
    }
}

// ---------------------------------------------------------------------------
// edge kernel: wave = 16 edges, TRANSPOSED (edge = lane&15 throughout).
// ---------------------------------------------------------------------------
__global__ void __launch_bounds__(256)
edge_mfma(const float* __restrict__ hE, const int* __restrict__ src,
          const int* __restrict__ dst, const float* __restrict__ logc,
          const unsigned short* __restrict__ Wf, const unsigned short* __restrict__ hVp,
          const float* __restrict__ pj,
          const float* __restrict__ b1, const float* __restrict__ b2,
          const float* __restrict__ b3, const int* __restrict__ slot,
          unsigned short* __restrict__ tg, int n_edges) {
    int lane = threadIdx.x & 63;
    int w    = threadIdx.x >> 6;
    int tile = blockIdx.x * 4 + w;
    int e0 = tile * 16;
    if (e0 >= n_edges) return;

    float c    = __expf(logc[0]);
    float scq  = sqrtf(c);
    float maxn = (1.0f - 1e-5f) / scq;

    int i15 = lane & 15, grp = lane >> 4;
    int ev = e0 + i15; if (ev >= n_edges) ev = n_edges - 1;
    int s16 = src[ev], d16 = dst[ev];

    const bf16x8* Wfrag = reinterpret_cast<const bf16x8*>(Wf);

    // node fragments: direct bf16 gather (projx pre-folded per node)
    const bf16x8* vsp = reinterpret_cast<const bf16x8*>(hVp + (size_t)s16 * 64);
    const bf16x8* vdp = reinterpret_cast<const bf16x8*>(hVp + (size_t)d16 * 64);
    bf16x8 aS0 = vsp[grp], aS1 = vsp[4 + grp];
    bf16x8 aD0 = vdp[grp], aD1 = vdp[4 + grp];
    float pjS = pj[s16], pjD = pj[d16];

    // hE: load per-lane k-chunks, squares, convert unscaled bf16
    float pE = 0.f;
    bf16x8 aE[6];
    const float* eb = hE + (size_t)ev * 192;
#pragma unroll
    for (int ks = 0; ks < 6; ++ks) {
        const float4* p4 = reinterpret_cast<const float4*>(eb + ks * 32 + grp * 8);
        float4 a0 = p4[0], a1 = p4[1];
        pE += a0.x*a0.x + a0.y*a0.y + a0.z*a0.z + a0.w*a0.w
            + a1.x*a1.x + a1.y*a1.y + a1.z*a1.z + a1.w*a1.w;
        union { bf16x8 b; unsigned u[4]; } cv;
        cv.u[0] = pkbf(a0.x, a0.y);
        cv.u[1] = pkbf(a0.z, a0.w);
        cv.u[2] = pkbf(a1.x, a1.y);
        cv.u[3] = pkbf(a1.z, a1.w);
        aE[ks] = cv.b;
    }
    pE += __shfl_xor(pE, 16); pE += __shfl_xor(pE, 32);
    float sE = fminf(maxn / fmaxf(sqrtf(pE), EPSF), 1.0f);
    float nt = sqrtf(sE * sE * pE + pjS + pjD);
    float gq = fast_atanh01(fminf(scq * nt, 1.0f - 1e-5f)) / (scq * (nt + EPSF));
    // sE, gq are per-lane (edge = i15) in the transposed scheme: no broadcast.

    // GEMM1 transposed: C^T = W * x^T  (A = weight frags, B = x frags)
    f32x4 accE[4] = {}, accV[4] = {};
#pragma unroll
    for (int ks = 0; ks < 6; ++ks) {
#pragma unroll
        for (int t = 0; t < 4; ++t)
            accE[t] = __builtin_amdgcn_mfma_f32_16x16x32_bf16(
                Wfrag[(size_t)(ks * 4 + t) * 64 + lane], aE[ks], accE[t], 0, 0, 0);
    }
#pragma unroll
    for (int t = 0; t < 4; ++t)
        accV[t] = __builtin_amdgcn_mfma_f32_16x16x32_bf16(
            Wfrag[(size_t)(24 + t) * 64 + lane], aS0, accV[t], 0, 0, 0);
#pragma unroll
    for (int t = 0; t < 4; ++t)
        accV[t] = __builtin_amdgcn_mfma_f32_16x16x32_bf16(
            Wfrag[(size_t)(28 + t) * 64 + lane], aS1, accV[t], 0, 0, 0);
#pragma unroll
    for (int t = 0; t < 4; ++t)
        accV[t] = __builtin_amdgcn_mfma_f32_16x16x32_bf16(
            Wfrag[(size_t)(32 + t) * 64 + lane], aD0, accV[t], 0, 0, 0);
#pragma unroll
    for (int t = 0; t < 4; ++t)
        accV[t] = __builtin_amdgcn_mfma_f32_16x16x32_bf16(
            Wfrag[(size_t)(36 + t) * 64 + lane], aD1, accV[t], 0, 0, 0);

    // epilogue 1: v = gq*(sE*accE + accV) + b1  (all per-lane scalars)
    float v[4][4];
#pragma unroll
    for (int t = 0; t < 4; ++t) {
        const float4 bv = *reinterpret_cast<const float4*>(&b1[t * 16 + 4 * grp]);
        v[t][0] = fmaf(gq, fmaf(sE, accE[t][0], accV[t][0]), bv.x);
        v[t][1] = fmaf(gq, fmaf(sE, accE[t][1], accV[t][1]), bv.y);
        v[t][2] = fmaf(gq, fmaf(sE, accE[t][2], accV[t][2]), bv.z);
        v[t][3] = fmaf(gq, fmaf(sE, accE[t][3], accV[t][3]), bv.w);
    }

    stage_mlp_t(v, Wfrag, 40, b2, scq, maxn, grp);
    stage_mlp_t(v, Wfrag, 48, b3, scq, maxn, grp);

    // tangent = logmap0(expmap0(v3)): per-lane factor, register store
    float n2 = 0.f;
#pragma unroll
    for (int t = 0; t < 4; ++t)
#pragma unroll
        for (int r = 0; r < 4; ++r) n2 = fmaf(v[t][r], v[t][r], n2);
    n2 += __shfl_xor(n2, 16); n2 += __shfl_xor(n2, 32);
    float n  = sqrtf(n2);
    float h  = fast_tanh_pos(scq * n) / (n * scq + EPSF);
    float hn = h * n;
    float g4 = fast_atanh01(fminf(scq * hn, 1.0f - 1e-5f)) / (scq * (hn + EPSF));
    float fT = g4 * h;

    if (e0 + i15 < n_edges) {
        int sl = slot[ev];
        unsigned short* orow = tg + (size_t)sl * 64;
#pragma unroll
        for (int t = 0; t < 4; ++t) {
            uint2 o;
            o.x = pkbf(fT * v[t][0], fT * v[t][1]);
            o.y = pkbf(fT * v[t][2], fT * v[t][3]);
            *reinterpret_cast<uint2*>(&orow[t * 16 + 4 * grp]) = o;
        }
    }
}

// ---------------------------------------------------------------------------
// node kernel: contiguous CSR range, 4 edges/iter (uint2 loads), then
// expmap0 -> mobius_add -> projx with wave reductions.
// ---------------------------------------------------------------------------
__global__ void __launch_bounds__(256)
node_gather(const float* __restrict__ hV, const float* __restrict__ logc,
            const unsigned short* __restrict__ tg, const int* __restrict__ rowptr,
            float* __restrict__ out, int n_nodes) {
    int wid  = (blockIdx.x * blockDim.x + threadIdx.x) >> 6;
    int lane = threadIdx.x & 63;
    if (wid >= n_nodes) return;

    float c    = __expf(logc[0]);
    float scq  = sqrtf(c);
    float maxn = (1.0f - 1e-5f) / scq;

    int beg = rowptr[wid], end = rowptr[wid + 1];
    int g = lane >> 4, i15 = lane & 15;
    // lane (g,i15) sums feats 4*i15..+3 over edges beg+g, beg+g+4, ...
    float s0 = 0.f, s1 = 0.f, s2 = 0.f, s3 = 0.f;
    for (int i = beg + g; i < end; i += 4) {
        uint2 p = *reinterpret_cast<const uint2*>(&tg[(size_t)i * 64 + i15 * 4]);
        s0 += bf2f((unsigned short)(p.x & 0xffff));
        s1 += bf2f((unsigned short)(p.x >> 16));
        s2 += bf2f((unsigned short)(p.y & 0xffff));
        s3 += bf2f((unsigned short)(p.y >> 16));
    }
    s0 += __shfl_xor(s0, 16); s0 += __shfl_xor(s0, 32);
    s1 += __shfl_xor(s1, 16); s1 += __shfl_xor(s1, 32);
    s2 += __shfl_xor(s2, 16); s2 += __shfl_xor(s2, 32);
    s3 += __shfl_xor(s3, 16); s3 += __shfl_xor(s3, 32);
    // redistribute: lane l wants feat l = chunk (l>>2), elem (l&3)
    int srcl = lane >> 2;
    float a0 = __shfl(s0, srcl), a1 = __shfl(s1, srcl);
    float a2 = __shfl(s2, srcl), a3 = __shfl(s3, srcl);
    float ssum = (lane & 2) ? ((lane & 1) ? a3 : a2) : ((lane & 1) ? a1 : a0);

    float inv = 1.f / fmaxf((float)(end - beg), 1.f);
    float at  = ssum * inv;

    float an2 = wred(at * at);
    float an  = sqrtf(an2);
    float ae  = fast_tanh_pos(scq * an) / (an * scq + EPSF);

    float xv  = hV[(size_t)wid * 64 + lane];
    float hs2 = wred(xv * xv);
    float sX  = fminf(maxn / fmaxf(sqrtf(hs2), EPSF), 1.0f);

    float x = sX * xv, y = ae * at;
    float x2 = wred(x * x);
    float y2 = wred(y * y);
    float xy = wred(x * y);

    float ca = 1.f + 2.f * c * xy + c * y2;
    float cb = 1.f - c * x2;
    float id = 1.f / (1.f + 2.f * c * xy + c * c * x2 * y2 + EPSF);

    float r   = (ca * x + cb * y) * id;
    float rn2 = wred(r * r);
    float rs  = fminf(maxn / fmaxf(sqrtf(rn2), EPSF), 1.0f);

    out[(size_t)wid * 64 + lane] = rs * r;
}

// ---------------------------------------------------------------------------
extern "C" void kernel_launch(void* const* d_in, const int* in_sizes, int n_in,
                              void* d_out, int out_size, void* d_ws, size_t ws_size,
                              hipStream_t stream) {
    const float* hV   = (const float*)d_in[0];
    const float* hE   = (const float*)d_in[1];
    const int*   src  = (const int*)d_in[2];
    const int*   dst  = (const int*)d_in[3];
    const float* logc = (const float*)d_in[4];
    const float* W1   = (const float*)d_in[5];
    const float* b1   = (const float*)d_in[6];
    const float* W2   = (const float*)d_in[7];
    const float* b2   = (const float*)d_in[8];
    const float* W3   = (const float*)d_in[9];
    const float* b3   = (const float*)d_in[10];

    int n_nodes = in_sizes[0] / 64;
    int n_edges = in_sizes[2];
    float* out = (float*)d_out;

    char* wsb = (char*)d_ws;
    unsigned short* Wf = (unsigned short*)wsb;                 // 56*512 ushort
    size_t off = 56 * 512 * sizeof(unsigned short);
    int* cnt    = (int*)(wsb + off);   off += (size_t)n_nodes * 4;
    int* rowptr = (int*)(wsb + off);   off += (size_t)(n_nodes + 1) * 4;
    int* slot   = (int*)(wsb + off);   off += (size_t)n_edges * 4;
    float* pj   = (float*)(wsb + off); off += (size_t)n_nodes * 4;
    off = (off + 15) & ~(size_t)15;
    unsigned short* hVp = (unsigned short*)(wsb + off);        // N*64 bf16
    off += (size_t)n_nodes * 64 * 2;
    off = (off + 15) & ~(size_t)15;
    unsigned short* tg = (unsigned short*)(wsb + off);         // E*64 bf16

    hipMemsetAsync(cnt, 0, (size_t)n_nodes * sizeof(int), stream);

    prep_wfrag<<<(56 * 64 + 255) / 256, 256, 0, stream>>>(W1, W2, W3, Wf);
    node_prep<<<(n_nodes + 3) / 4, 256, 0, stream>>>(hV, logc, hVp, pj, n_nodes);
    hist_kernel<<<(n_edges + 255) / 256, 256, 0, stream>>>(src, cnt, slot, n_edges);
    scan_rowptr<<<1, 1024, 0, stream>>>(cnt, rowptr, n_nodes);
    slotfix_kernel<<<(n_edges + 255) / 256, 256, 0, stream>>>(src, rowptr, slot, n_edges);

    int tiles = (n_edges + 15) / 16;
    edge_mfma<<<(tiles + 3) / 4, 256, 0, stream>>>(
        hE, src, dst, logc, Wf, hVp, pj, b1, b2, b3, slot, tg, n_edges);

    node_gather<<<(n_nodes + 3) / 4, 256, 0, stream>>>(
        hV, logc, tg, rowptr, out, n_nodes);
}